// Round 1
// baseline (305.169 us; speedup 1.0000x reference)
//
#include <hip/hip_runtime.h>
#include <hip/hip_bf16.h>
#include <stdint.h>

#define HEADS 16
#define HD 64
#define SEQ 2048
#define BATCH 2
#define CDIM 1024
#define MROWS (BATCH*SEQ)   // 4096
#define K3C (3*CDIM)        // 3072
// Q prescale: attn scale 1/8 times log2(e), so softmax uses exp2 directly
#define QSCALE 0.1803368801111244f

typedef __bf16 bf16x8 __attribute__((ext_vector_type(8)));
typedef float  f32x4  __attribute__((ext_vector_type(4)));

__device__ __forceinline__ unsigned short f2bf(float f) {
    __hip_bfloat16 h = __float2bfloat16(f);
    return __builtin_bit_cast(unsigned short, h);
}
__device__ __forceinline__ unsigned int pack2bf(float a, float b) {
    return (unsigned int)f2bf(a) | ((unsigned int)f2bf(b) << 16);
}
__device__ __forceinline__ bf16x8 frag(uint4 u) { return __builtin_bit_cast(bf16x8, u); }

// async global->LDS: per-lane global gather -> contiguous LDS (base + lane*16)
__device__ __forceinline__ void async16(const unsigned short* g, unsigned short* lds) {
    __builtin_amdgcn_global_load_lds(
        (const __attribute__((address_space(1))) unsigned int*)g,
        (__attribute__((address_space(3))) unsigned int*)lds, 16, 0, 0);
}

// ---------------- fused cast kernel ----------------
__global__ void cast_all(const float* __restrict__ q, const float* __restrict__ k,
                         const float* __restrict__ v, const float* __restrict__ Wq,
                         const float* __restrict__ Wp,
                         unsigned short* __restrict__ A, unsigned short* __restrict__ Wqb,
                         unsigned short* __restrict__ Wpb)
{
    const int bid = blockIdx.x;
    const int t = threadIdx.x;
    if (bid < MROWS) {
        const float* srcs[3] = {q, k, v};
        #pragma unroll
        for (int i = 0; i < 3; ++i) {
            float4 f = *(const float4*)(srcs[i] + (size_t)bid*CDIM + t*4);
            ushort4 s;
            s.x = f2bf(f.x); s.y = f2bf(f.y); s.z = f2bf(f.z); s.w = f2bf(f.w);
            *(ushort4*)(A + (size_t)bid*K3C + i*CDIM + t*4) = s;
        }
    } else if (bid < MROWS + 9216) {
        int idx = (bid - MROWS)*256 + t;
        float4 f = ((const float4*)Wq)[idx];
        ushort4 s;
        s.x = f2bf(f.x); s.y = f2bf(f.y); s.z = f2bf(f.z); s.w = f2bf(f.w);
        ((ushort4*)Wqb)[idx] = s;
    } else {
        int idx = (bid - MROWS - 9216)*256 + t;
        float4 f = ((const float4*)Wp)[idx];
        ushort4 s;
        s.x = f2bf(f.x); s.y = f2bf(f.y); s.z = f2bf(f.z); s.w = f2bf(f.w);
        ((ushort4*)Wpb)[idx] = s;
    }
}

// ---------------- m97-style bf16 GEMM (BK=32) — kept for the proj GEMM ----------------
template<int EPI>
__global__ __launch_bounds__(256, 2)
void gemm_bt(const unsigned short* __restrict__ A, const unsigned short* __restrict__ B,
             int M, int N, int K,
             unsigned short* __restrict__ qh, unsigned short* __restrict__ kh,
             unsigned short* __restrict__ vt,
             const float* __restrict__ bias, float* __restrict__ out)
{
    __shared__ __attribute__((aligned(16))) unsigned short As[128*32];
    __shared__ __attribute__((aligned(16))) unsigned short Bs[128*32];
    const int tid  = threadIdx.x;
    const int wave = tid >> 6;
    const int lane = tid & 63;
    const int l15  = lane & 15;
    const int quad = lane >> 4;
    const int wm = (wave >> 1) * 64;
    const int wn = (wave & 1) * 64;
    const int m0 = blockIdx.x * 128;
    const int n0 = blockIdx.y * 128;

    f32x4 acc[4][4] = {};

    const int srow = tid >> 2;
    const int sc8  = (tid & 3) * 8;

    for (int k0 = 0; k0 < K; k0 += 32) {
        #pragma unroll
        for (int t = 0; t < 2; ++t) {
            int row = t*64 + srow;
            const unsigned short* ga = A + (size_t)(m0 + row)*K + k0 + sc8;
            const unsigned short* gb = B + (size_t)(n0 + row)*K + k0 + sc8;
            async16(ga, &As[(t*256 + wave*64)*8]);
            async16(gb, &Bs[(t*256 + wave*64)*8]);
        }
        __syncthreads();
        uint4 af[4], bfv[4];
        #pragma unroll
        for (int i = 0; i < 4; ++i) {
            af[i]  = *(const uint4*)&As[(wm + i*16 + l15)*32 + quad*8];
            bfv[i] = *(const uint4*)&Bs[(wn + i*16 + l15)*32 + quad*8];
        }
        #pragma unroll
        for (int mi = 0; mi < 4; ++mi)
            #pragma unroll
            for (int ni = 0; ni < 4; ++ni)
                acc[mi][ni] = __builtin_amdgcn_mfma_f32_16x16x32_bf16(
                    frag(af[mi]), frag(bfv[ni]), acc[mi][ni], 0, 0, 0);
        __syncthreads();
    }

    if constexpr (EPI == 0) {
        #pragma unroll
        for (int mi = 0; mi < 4; ++mi) {
            int row0 = m0 + wm + mi*16 + quad*4;
            int b  = row0 >> 11;
            int nq = row0 & 2047;
            #pragma unroll
            for (int ni = 0; ni < 4; ++ni) {
                int col   = n0 + wn + ni*16 + l15;
                int which = col >> 10;
                int h     = (col >> 6) & 15;
                int d     = col & 63;
                int bh    = b*HEADS + h;
                if (which == 2) {
                    ushort4 pv;
                    pv.x = f2bf(acc[mi][ni][0]);
                    pv.y = f2bf(acc[mi][ni][1]);
                    pv.z = f2bf(acc[mi][ni][2]);
                    pv.w = f2bf(acc[mi][ni][3]);
                    *(ushort4*)&vt[((size_t)bh*HD + d)*SEQ + nq] = pv;
                } else {
                    unsigned short* dst = (which == 0) ? qh : kh;
                    float sc = (which == 0) ? QSCALE : 1.0f;
                    #pragma unroll
                    for (int r = 0; r < 4; ++r)
                        dst[((size_t)bh*SEQ + nq + r)*HD + d] = f2bf(acc[mi][ni][r] * sc);
                }
            }
        }
    } else {
        #pragma unroll
        for (int mi = 0; mi < 4; ++mi) {
            int row0 = m0 + wm + mi*16 + quad*4;
            #pragma unroll
            for (int ni = 0; ni < 4; ++ni) {
                int col  = n0 + wn + ni*16 + l15;
                float bv = bias[col];
                #pragma unroll
                for (int r = 0; r < 4; ++r)
                    out[(size_t)(row0 + r)*N + col] = acc[mi][ni][r] + bv;
            }
        }
    }
}

// ---------------- 256x256 8-phase bf16 GEMM for the QKV projection ----------------
// T1 XCD swizzle + T2 st_16x32 LDS swizzle (inverse-swizzled global src, linear
// global_load_lds dest, swizzled ds_read) + T3/T4 counted vmcnt(6) + T5 setprio.
// 8 waves (2M x 4N), BK=64, per-wave 128x64 output, acc[8][4].
// LDS 128 KiB: A/B each 2 dbuf x 2 regions x 16 KiB.
//   A region g holds rows {[0,64)+[128,192)} (g=0) / {[64,128)+[192,256)} (g=1):
//     exactly what miL / miH phases consume.  B region g likewise by 32-row
//     slices per wc so niL / niH phases each touch only one region.
// Region layout: [8 rowsub][2 colsub][16][32] bf16, byte ^= ((byte>>9)&1)<<5.
// Stage slots: P1 -> B_H(t+1), P2 -> A_L(t+2), P3 -> B_L(t+2), P4 -> A_H(t+2);
// each half is staged only after the phase whose barrier retired its last read.
// One s_waitcnt vmcnt(6) per tile at P4 (3 half-tiles = 6 loads stay in flight);
// drains to vmcnt(0) only at tile NT-2.
#define NT48 48

__global__ __launch_bounds__(512, 2)
void gemm256_qkv(const unsigned short* __restrict__ A, const unsigned short* __restrict__ B,
                 unsigned short* __restrict__ qh, unsigned short* __restrict__ kh,
                 unsigned short* __restrict__ vt)
{
    __shared__ __attribute__((aligned(16))) unsigned short As[2*16384];
    __shared__ __attribute__((aligned(16))) unsigned short Bs[2*16384];

    const int tid  = threadIdx.x;
    const int wave = tid >> 6;
    const int lane = tid & 63;
    const int l15  = lane & 15;
    const int quad = lane >> 4;
    const int wr   = wave >> 2;   // 0..1  (M)
    const int wc   = wave & 3;    // 0..3  (N)

    // XCD-aware bijective swizzle: 192 blocks, 192 % 8 == 0
    const int id  = blockIdx.x;
    const int swz = (id & 7)*24 + (id >> 3);
    const int m0  = (swz & 15) * 256;   // 16 M-tiles
    const int n0  = (swz >> 4) * 256;   // 12 N-tiles

    // staging decode: LDS linear 16B chunk p -> (local row, k elem) via inverse swizzle
    int lrr[2], kel[2];
    #pragma unroll
    for (int j = 0; j < 2; ++j) {
        int p  = (j*512 + tid) * 16;            // byte within 16KB region
        int st = p >> 10;                       // subtile 0..15
        int q  = p & 1023;
        int ql = q ^ (((q >> 9) & 1) << 5);     // inverse st_16x32 (involution)
        lrr[j] = (st >> 1)*16 + (ql >> 6);      // local row 0..127
        kel[j] = (st & 1)*32 + ((ql & 63) >> 1);// k element 0..63
    }
    const int ldsc = wave*64*8;  // wave-uniform chunk base (ushorts); +j*4096

    auto stageA = [&](int t, int g) {
        unsigned short* dst = As + (t & 1)*16384 + g*8192;
        #pragma unroll
        for (int j = 0; j < 2; ++j) {
            int grow = (lrr[j] >> 6)*128 + g*64 + (lrr[j] & 63);
            async16(A + (size_t)(m0 + grow)*K3C + t*64 + kel[j], dst + j*4096 + ldsc);
        }
    };
    auto stageB = [&](int t, int g) {
        unsigned short* dst = Bs + (t & 1)*16384 + g*8192;
        #pragma unroll
        for (int j = 0; j < 2; ++j) {
            int grow = (lrr[j] >> 5)*64 + g*32 + (lrr[j] & 31);
            async16(B + (size_t)(n0 + grow)*K3C + t*64 + kel[j], dst + j*4096 + ldsc);
        }
    };

    // per-lane swizzled ds_read base (ushorts); frag = base + immediate offset
    const int laneoff = (((l15*64 + quad*16) ^ ((l15 & 8) << 2)) >> 1);

    f32x4 acc[8][4] = {};

    // prologue: tile0 fully + tile1 {A_L,B_L,A_H}; B_H(1) is issued in t=0 P1.
    stageA(0, 0); stageB(0, 0); stageA(0, 1); stageB(0, 1);
    stageA(1, 0); stageB(1, 0); stageA(1, 1);
    asm volatile("s_waitcnt vmcnt(6)" ::: "memory");   // tile0's 8 loads landed
    __builtin_amdgcn_s_barrier();

    for (int tt = 0; tt < NT48; tt += 2) {
        #pragma unroll
        for (int hb = 0; hb < 2; ++hb) {
            const int t = tt + hb;                       // t&1 == hb
            const unsigned short* Ab = As + hb*16384 + laneoff;
            const unsigned short* Bb = Bs + hb*16384 + laneoff;
            uint4 ar[4][2], bl[2][2], bh[2][2];

            // ---- P1: ds-read A_L + B_L | stage B_H(t+1) | MFMA (mi 0-3, ni 0-1)
            #pragma unroll
            for (int mi = 0; mi < 4; ++mi)
                #pragma unroll
                for (int kc = 0; kc < 2; ++kc)
                    ar[mi][kc] = *(const uint4*)&Ab[((wr*4 + mi)*2 + kc)*512];
            #pragma unroll
            for (int ni = 0; ni < 2; ++ni)
                #pragma unroll
                for (int kc = 0; kc < 2; ++kc)
                    bl[ni][kc] = *(const uint4*)&Bb[((wc*2 + ni)*2 + kc)*512];
            if (t + 1 < NT48) stageB(t + 1, 1);
            __builtin_amdgcn_s_barrier();
            __builtin_amdgcn_s_setprio(1);
            #pragma unroll
            for (int mi = 0; mi < 4; ++mi)
                #pragma unroll
                for (int ni = 0; ni < 2; ++ni)
                    #pragma unroll
                    for (int kc = 0; kc < 2; ++kc)
                        acc[mi][ni] = __builtin_amdgcn_mfma_f32_16x16x32_bf16(
                            frag(ar[mi][kc]), frag(bl[ni][kc]), acc[mi][ni], 0, 0, 0);
            __builtin_amdgcn_s_setprio(0);
            __builtin_amdgcn_s_barrier();

            // ---- P2: ds-read B_H | stage A_L(t+2) | MFMA (mi 0-3, ni 2-3)
            #pragma unroll
            for (int ni = 0; ni < 2; ++ni)
                #pragma unroll
                for (int kc = 0; kc < 2; ++kc)
                    bh[ni][kc] = *(const uint4*)&Bb[8192 + ((wc*2 + ni)*2 + kc)*512];
            if (t + 2 < NT48) stageA(t + 2, 0);
            __builtin_amdgcn_s_barrier();
            __builtin_amdgcn_s_setprio(1);
            #pragma unroll
            for (int mi = 0; mi < 4; ++mi)
                #pragma unroll
                for (int ni = 0; ni < 2; ++ni)
                    #pragma unroll
                    for (int kc = 0; kc < 2; ++kc)
                        acc[mi][ni+2] = __builtin_amdgcn_mfma_f32_16x16x32_bf16(
                            frag(ar[mi][kc]), frag(bh[ni][kc]), acc[mi][ni+2], 0, 0, 0);
            __builtin_amdgcn_s_setprio(0);
            __builtin_amdgcn_s_barrier();

            // ---- P3: ds-read A_H | stage B_L(t+2) | MFMA (mi 4-7, ni 0-1)
            #pragma unroll
            for (int mi = 0; mi < 4; ++mi)
                #pragma unroll
                for (int kc = 0; kc < 2; ++kc)
                    ar[mi][kc] = *(const uint4*)&Ab[8192 + ((wr*4 + mi)*2 + kc)*512];
            if (t + 2 < NT48) stageB(t + 2, 0);
            __builtin_amdgcn_s_barrier();
            __builtin_amdgcn_s_setprio(1);
            #pragma unroll
            for (int mi = 0; mi < 4; ++mi)
                #pragma unroll
                for (int ni = 0; ni < 2; ++ni)
                    #pragma unroll
                    for (int kc = 0; kc < 2; ++kc)
                        acc[mi+4][ni] = __builtin_amdgcn_mfma_f32_16x16x32_bf16(
                            frag(ar[mi][kc]), frag(bl[ni][kc]), acc[mi+4][ni], 0, 0, 0);
            __builtin_amdgcn_s_setprio(0);
            __builtin_amdgcn_s_barrier();

            // ---- P4: stage A_H(t+2) | counted vmcnt | MFMA (mi 4-7, ni 2-3)
            if (t + 2 < NT48) stageA(t + 2, 1);
            if (t + 2 < NT48)      { asm volatile("s_waitcnt vmcnt(6)" ::: "memory"); }
            else if (t + 1 < NT48) { asm volatile("s_waitcnt vmcnt(0)" ::: "memory"); }
            __builtin_amdgcn_s_barrier();
            __builtin_amdgcn_s_setprio(1);
            #pragma unroll
            for (int mi = 0; mi < 4; ++mi)
                #pragma unroll
                for (int ni = 0; ni < 2; ++ni)
                    #pragma unroll
                    for (int kc = 0; kc < 2; ++kc)
                        acc[mi+4][ni+2] = __builtin_amdgcn_mfma_f32_16x16x32_bf16(
                            frag(ar[mi][kc]), frag(bh[ni][kc]), acc[mi+4][ni+2], 0, 0, 0);
            __builtin_amdgcn_s_setprio(0);
            __builtin_amdgcn_s_barrier();
        }
    }

    // epilogue: route into qh (scaled), kh, vt (transposed) — same mapping as before
    #pragma unroll
    for (int mi = 0; mi < 8; ++mi) {
        const int row0 = m0 + wr*128 + mi*16 + quad*4;
        const int b  = row0 >> 11;
        const int nq = row0 & 2047;
        #pragma unroll
        for (int ni = 0; ni < 4; ++ni) {
            const int col   = n0 + wc*64 + ni*16 + l15;
            const int which = col >> 10;
            const int h     = (col >> 6) & 15;
            const int d     = col & 63;
            const int bh_   = b*HEADS + h;
            if (which == 2) {
                ushort4 pv;
                pv.x = f2bf(acc[mi][ni][0]);
                pv.y = f2bf(acc[mi][ni][1]);
                pv.z = f2bf(acc[mi][ni][2]);
                pv.w = f2bf(acc[mi][ni][3]);
                *(ushort4*)&vt[((size_t)bh_*HD + d)*SEQ + nq] = pv;
            } else {
                unsigned short* dst = (which == 0) ? qh : kh;
                float sc = (which == 0) ? QSCALE : 1.0f;
                #pragma unroll
                for (int r = 0; r < 4; ++r)
                    dst[((size_t)bh_*SEQ + nq + r)*HD + d] = f2bf(acc[mi][ni][r] * sc);
            }
        }
    }
}

// ---------------- flash attention: 32 q/wave + async double-buffered K/V ----------------
__global__ __launch_bounds__(256, 2)
void attention(const unsigned short* __restrict__ qh, const unsigned short* __restrict__ kh,
               const unsigned short* __restrict__ vt, unsigned short* __restrict__ xb)
{
    const int qt = blockIdx.x;          // 0..15 (tiles of 128 q)
    const int h  = blockIdx.y;
    const int b  = blockIdx.z;
    const int bh = b*HEADS + h;
    const int tid  = threadIdx.x;
    const int wave = tid >> 6;
    const int lane = tid & 63;
    const int l15  = lane & 15;
    const int quad = lane >> 4;

    __shared__ __attribute__((aligned(16))) unsigned short Ks[2][64*64];
    __shared__ __attribute__((aligned(16))) unsigned short Vs[2][64*64];
    __shared__ __attribute__((aligned(16))) unsigned short Ps[4][2*16*72];

    const unsigned short* Qp = qh + ((size_t)bh*SEQ + qt*128 + wave*32)*HD;
    const unsigned short* Kp = kh + (size_t)bh*SEQ*HD;
    const unsigned short* Vp = vt + (size_t)bh*HD*SEQ;

    auto stage = [&](int kt, int bufI) {
        #pragma unroll
        for (int t = 0; t < 2; ++t) {
            int c  = t*256 + wave*64 + lane;   // chunk index 0..511
            int r  = c >> 3;
            int cc = (c & 7) ^ (r & 7);
            async16(Kp + (size_t)(kt*64 + r)*HD + cc*8,
                    &Ks[bufI][(t*256 + wave*64)*8]);
            async16(Vp + (size_t)r*SEQ + kt*64 + cc*8,
                    &Vs[bufI][(t*256 + wave*64)*8]);
        }
    };

    stage(0, 0);

    uint4 qf[2][2];
    #pragma unroll
    for (int g = 0; g < 2; ++g) {
        qf[g][0] = *(const uint4*)(Qp + (size_t)(g*16 + l15)*HD + quad*8);
        qf[g][1] = *(const uint4*)(Qp + (size_t)(g*16 + l15)*HD + 32 + quad*8);
    }

    f32x4 o[2][4] = {};
    float m_s[2] = {-INFINITY, -INFINITY};
    float l_s[2] = {0.f, 0.f};

    unsigned short* Pw = Ps[wave];
    const int x7 = l15 & 7;

    for (int kt = 0; kt < SEQ/64; ++kt) {
        stage((kt + 1) & 31, (kt + 1) & 1);
        asm volatile("s_waitcnt vmcnt(4)" ::: "memory");
        asm volatile("s_barrier" ::: "memory");

        const unsigned short* Kb = Ks[kt & 1];
        const unsigned short* Vb = Vs[kt & 1];

        f32x4 s[2][4];
        #pragma unroll
        for (int st = 0; st < 4; ++st) {
            int rb = st*16 + l15;
            uint4 kf0 = *(const uint4*)&Kb[(rb*8 + (quad ^ x7))*8];
            uint4 kf1 = *(const uint4*)&Kb[(rb*8 + ((4 + quad) ^ x7))*8];
            #pragma unroll
            for (int g = 0; g < 2; ++g) {
                f32x4 z = {};
                z = __builtin_amdgcn_mfma_f32_16x16x32_bf16(frag(kf0), frag(qf[g][0]), z, 0, 0, 0);
                z = __builtin_amdgcn_mfma_f32_16x16x32_bf16(frag(kf1), frag(qf[g][1]), z, 0, 0, 0);
                s[g][st] = z;
            }
        }

        #pragma unroll
        for (int g = 0; g < 2; ++g) {
            float mloc = s[g][0][0];
            #pragma unroll
            for (int st = 0; st < 4; ++st)
                #pragma unroll
                for (int r = 0; r < 4; ++r)
                    mloc = fmaxf(mloc, s[g][st][r]);
            mloc = fmaxf(mloc, __shfl_xor(mloc, 16));
            mloc = fmaxf(mloc, __shfl_xor(mloc, 32));

            float mn = fmaxf(m_s[g], mloc);
            float al = __builtin_amdgcn_exp2f(m_s[g] - mn);
            m_s[g] = mn;

            float rs = 0.f;
            float p[4][4];
            #pragma unroll
            for (int st = 0; st < 4; ++st)
                #pragma unroll
                for (int r = 0; r < 4; ++r) {
                    p[st][r] = __builtin_amdgcn_exp2f(s[g][st][r] - mn);
                    rs += p[st][r];
                }
            rs += __shfl_xor(rs, 16);
            rs += __shfl_xor(rs, 32);
            l_s[g] = al*l_s[g] + rs;

            #pragma unroll
            for (int st = 0; st < 4; ++st)
                #pragma unroll
                for (int r = 0; r < 4; ++r)
                    o[g][st][r] *= al;

            #pragma unroll
            for (int st = 0; st < 4; ++st) {
                uint2 pk;
                pk.x = pack2bf(p[st][0], p[st][1]);
                pk.y = pack2bf(p[st][2], p[st][3]);
                *(uint2*)&Pw[g*1152 + l15*72 + st*16 + quad*4] = pk;
            }
        }
        asm volatile("s_waitcnt lgkmcnt(0)" ::: "memory");

        uint4 pB[2][2];
        #pragma unroll
        for (int g = 0; g < 2; ++g) {
            pB[g][0] = *(const uint4*)&Pw[g*1152 + l15*72 + quad*8];
            pB[g][1] = *(const uint4*)&Pw[g*1152 + l15*72 + 32 + quad*8];
        }

        #pragma unroll
        for (int st = 0; st < 4; ++st) {
            int rb = st*16 + l15;
            uint4 vf0 = *(const uint4*)&Vb[(rb*8 + (quad ^ x7))*8];
            uint4 vf1 = *(const uint4*)&Vb[(rb*8 + ((4 + quad) ^ x7))*8];
            #pragma unroll
            for (int g = 0; g < 2; ++g) {
                o[g][st] = __builtin_amdgcn_mfma_f32_16x16x32_bf16(frag(vf0), frag(pB[g][0]), o[g][st], 0, 0, 0);
                o[g][st] = __builtin_amdgcn_mfma_f32_16x16x32_bf16(frag(vf1), frag(pB[g][1]), o[g][st], 0, 0, 0);
            }
        }

        asm volatile("s_barrier" ::: "memory");
    }

    #pragma unroll
    for (int g = 0; g < 2; ++g) {
        float inv = 1.0f / l_s[g];
        #pragma unroll
        for (int st = 0; st < 4; ++st) {
            uint2 pk;
            pk.x = pack2bf(o[g][st][0]*inv, o[g][st][1]*inv);
            pk.y = pack2bf(o[g][st][2]*inv, o[g][st][3]*inv);
            *(uint2*)&Pw[g*1152 + l15*72 + st*16 + quad*4] = pk;
        }
    }
    asm volatile("s_waitcnt lgkmcnt(0)" ::: "memory");

    const int qr = lane >> 2;          // 0..15
    const int dd = (lane & 3) * 16;    // 0,16,32,48
    #pragma unroll
    for (int g = 0; g < 2; ++g) {
        uint4 oa = *(const uint4*)&Pw[g*1152 + qr*72 + dd];
        uint4 ob = *(const uint4*)&Pw[g*1152 + qr*72 + dd + 8];
        const int mrow = b*SEQ + qt*128 + wave*32 + g*16 + qr;
        *(uint4*)&xb[(size_t)mrow*CDIM + h*HD + dd]     = oa;
        *(uint4*)&xb[(size_t)mrow*CDIM + h*HD + dd + 8] = ob;
    }
}

extern "C" void kernel_launch(void* const* d_in, const int* in_sizes, int n_in,
                              void* d_out, int out_size, void* d_ws, size_t ws_size,
                              hipStream_t stream)
{
    const float* q  = (const float*)d_in[0];
    const float* k  = (const float*)d_in[1];
    const float* v  = (const float*)d_in[2];
    const float* Wq = (const float*)d_in[3];
    const float* Wp = (const float*)d_in[4];
    const float* bp = (const float*)d_in[5];
    float* out = (float*)d_out;

    char* p = (char*)d_ws;
    auto carve = [&](size_t bytes) { char* r = p; p += (bytes + 255) & ~(size_t)255; return r; };
    unsigned short* Abuf   = (unsigned short*)carve((size_t)MROWS*K3C*2);
    unsigned short* Wqkvb  = (unsigned short*)carve((size_t)K3C*K3C*2);
    unsigned short* Wprojb = (unsigned short*)carve((size_t)CDIM*CDIM*2);
    unsigned short* qhb    = (unsigned short*)carve((size_t)BATCH*HEADS*SEQ*HD*2);
    unsigned short* khb    = (unsigned short*)carve((size_t)BATCH*HEADS*SEQ*HD*2);
    unsigned short* vtb    = (unsigned short*)carve((size_t)BATCH*HEADS*SEQ*HD*2);
    unsigned short* xbuf   = (unsigned short*)carve((size_t)MROWS*CDIM*2);

    cast_all<<<MROWS + 9216 + 1024, 256, 0, stream>>>(q, k, v, Wq, Wp, Abuf, Wqkvb, Wprojb);

    gemm256_qkv<<<dim3(192), 512, 0, stream>>>(Abuf, Wqkvb, qhb, khb, vtb);

    attention<<<dim3(SEQ/128, HEADS, BATCH), 256, 0, stream>>>(qhb, khb, vtb, xbuf);

    gemm_bt<1><<<dim3(MROWS/128, CDIM/128), 256, 0, stream>>>(
        xbuf, Wprojb, MROWS, CDIM, CDIM, nullptr, nullptr, nullptr, bp, out);
}

// Round 2
// 300.543 us; speedup vs baseline: 1.0154x; 1.0154x over previous
//
#include <hip/hip_runtime.h>
#include <hip/hip_bf16.h>
#include <stdint.h>

#define HEADS 16
#define HD 64
#define SEQ 2048
#define BATCH 2
#define CDIM 1024
#define MROWS (BATCH*SEQ)   // 4096
#define K3C (3*CDIM)        // 3072
// Q prescale: attn scale 1/8 times log2(e), so softmax uses exp2 directly
#define QSCALE 0.1803368801111244f

typedef __bf16 bf16x8 __attribute__((ext_vector_type(8)));
typedef float  f32x4  __attribute__((ext_vector_type(4)));

__device__ __forceinline__ unsigned short f2bf(float f) {
    __hip_bfloat16 h = __float2bfloat16(f);
    return __builtin_bit_cast(unsigned short, h);
}
__device__ __forceinline__ unsigned int pack2bf(float a, float b) {
    return (unsigned int)f2bf(a) | ((unsigned int)f2bf(b) << 16);
}
__device__ __forceinline__ bf16x8 frag(uint4 u) { return __builtin_bit_cast(bf16x8, u); }

// async global->LDS: per-lane global gather -> contiguous LDS (base + lane*16)
__device__ __forceinline__ void async16(const unsigned short* g, unsigned short* lds) {
    __builtin_amdgcn_global_load_lds(
        (const __attribute__((address_space(1))) unsigned int*)g,
        (__attribute__((address_space(3))) unsigned int*)lds, 16, 0, 0);
}

// inline-asm ds_read_b128: hidden from the compiler's LDS-DMA hazard pass so the
// counted vmcnt(6) pipeline survives (plain C++ LDS loads after global_load_lds
// get conservative vmcnt drains inserted -> pipeline collapses to 1-phase perf).
__device__ __forceinline__ void dsr(uint4& d, unsigned addr, unsigned imm) {
    asm volatile("ds_read_b128 %0, %1 offset:%c2" : "=v"(d) : "v"(addr), "i"(imm));
}

// ---------------- fused cast kernel ----------------
__global__ void cast_all(const float* __restrict__ q, const float* __restrict__ k,
                         const float* __restrict__ v, const float* __restrict__ Wq,
                         const float* __restrict__ Wp,
                         unsigned short* __restrict__ A, unsigned short* __restrict__ Wqb,
                         unsigned short* __restrict__ Wpb)
{
    const int bid = blockIdx.x;
    const int t = threadIdx.x;
    if (bid < MROWS) {
        const float* srcs[3] = {q, k, v};
        #pragma unroll
        for (int i = 0; i < 3; ++i) {
            float4 f = *(const float4*)(srcs[i] + (size_t)bid*CDIM + t*4);
            ushort4 s;
            s.x = f2bf(f.x); s.y = f2bf(f.y); s.z = f2bf(f.z); s.w = f2bf(f.w);
            *(ushort4*)(A + (size_t)bid*K3C + i*CDIM + t*4) = s;
        }
    } else if (bid < MROWS + 9216) {
        int idx = (bid - MROWS)*256 + t;
        float4 f = ((const float4*)Wq)[idx];
        ushort4 s;
        s.x = f2bf(f.x); s.y = f2bf(f.y); s.z = f2bf(f.z); s.w = f2bf(f.w);
        ((ushort4*)Wqb)[idx] = s;
    } else {
        int idx = (bid - MROWS - 9216)*256 + t;
        float4 f = ((const float4*)Wp)[idx];
        ushort4 s;
        s.x = f2bf(f.x); s.y = f2bf(f.y); s.z = f2bf(f.z); s.w = f2bf(f.w);
        ((ushort4*)Wpb)[idx] = s;
    }
}

// ---------------- m97-style bf16 GEMM (BK=32) — kept for the proj GEMM ----------------
template<int EPI>
__global__ __launch_bounds__(256, 2)
void gemm_bt(const unsigned short* __restrict__ A, const unsigned short* __restrict__ B,
             int M, int N, int K,
             unsigned short* __restrict__ qh, unsigned short* __restrict__ kh,
             unsigned short* __restrict__ vt,
             const float* __restrict__ bias, float* __restrict__ out)
{
    __shared__ __attribute__((aligned(16))) unsigned short As[128*32];
    __shared__ __attribute__((aligned(16))) unsigned short Bs[128*32];
    const int tid  = threadIdx.x;
    const int wave = tid >> 6;
    const int lane = tid & 63;
    const int l15  = lane & 15;
    const int quad = lane >> 4;
    const int wm = (wave >> 1) * 64;
    const int wn = (wave & 1) * 64;
    const int m0 = blockIdx.x * 128;
    const int n0 = blockIdx.y * 128;

    f32x4 acc[4][4] = {};

    const int srow = tid >> 2;
    const int sc8  = (tid & 3) * 8;

    for (int k0 = 0; k0 < K; k0 += 32) {
        #pragma unroll
        for (int t = 0; t < 2; ++t) {
            int row = t*64 + srow;
            const unsigned short* ga = A + (size_t)(m0 + row)*K + k0 + sc8;
            const unsigned short* gb = B + (size_t)(n0 + row)*K + k0 + sc8;
            async16(ga, &As[(t*256 + wave*64)*8]);
            async16(gb, &Bs[(t*256 + wave*64)*8]);
        }
        __syncthreads();
        uint4 af[4], bfv[4];
        #pragma unroll
        for (int i = 0; i < 4; ++i) {
            af[i]  = *(const uint4*)&As[(wm + i*16 + l15)*32 + quad*8];
            bfv[i] = *(const uint4*)&Bs[(wn + i*16 + l15)*32 + quad*8];
        }
        #pragma unroll
        for (int mi = 0; mi < 4; ++mi)
            #pragma unroll
            for (int ni = 0; ni < 4; ++ni)
                acc[mi][ni] = __builtin_amdgcn_mfma_f32_16x16x32_bf16(
                    frag(af[mi]), frag(bfv[ni]), acc[mi][ni], 0, 0, 0);
        __syncthreads();
    }

    if constexpr (EPI == 0) {
        #pragma unroll
        for (int mi = 0; mi < 4; ++mi) {
            int row0 = m0 + wm + mi*16 + quad*4;
            int b  = row0 >> 11;
            int nq = row0 & 2047;
            #pragma unroll
            for (int ni = 0; ni < 4; ++ni) {
                int col   = n0 + wn + ni*16 + l15;
                int which = col >> 10;
                int h     = (col >> 6) & 15;
                int d     = col & 63;
                int bh    = b*HEADS + h;
                if (which == 2) {
                    ushort4 pv;
                    pv.x = f2bf(acc[mi][ni][0]);
                    pv.y = f2bf(acc[mi][ni][1]);
                    pv.z = f2bf(acc[mi][ni][2]);
                    pv.w = f2bf(acc[mi][ni][3]);
                    *(ushort4*)&vt[((size_t)bh*HD + d)*SEQ + nq] = pv;
                } else {
                    unsigned short* dst = (which == 0) ? qh : kh;
                    float sc = (which == 0) ? QSCALE : 1.0f;
                    #pragma unroll
                    for (int r = 0; r < 4; ++r)
                        dst[((size_t)bh*SEQ + nq + r)*HD + d] = f2bf(acc[mi][ni][r] * sc);
                }
            }
        }
    } else {
        #pragma unroll
        for (int mi = 0; mi < 4; ++mi) {
            int row0 = m0 + wm + mi*16 + quad*4;
            #pragma unroll
            for (int ni = 0; ni < 4; ++ni) {
                int col  = n0 + wn + ni*16 + l15;
                float bv = bias[col];
                #pragma unroll
                for (int r = 0; r < 4; ++r)
                    out[(size_t)(row0 + r)*N + col] = acc[mi][ni][r] + bv;
            }
        }
    }
}

// ---------------- 256x256 8-phase bf16 GEMM for the QKV projection ----------------
// Same geometry as round 1 (T1 XCD swizzle, T2 st_16x32 swizzle, T3/T4 counted
// vmcnt(6), T5 setprio).  Delta this round: all in-loop LDS fragment reads are
// inline-asm ds_read_b128 (base VGPR + compile-time offset), with explicit
// s_waitcnt lgkmcnt(0) + sched_barrier(0) before each MFMA cluster (rule #18).
// This hides the reads from the LDS-DMA hazard tracker so the counted-vmcnt
// pipeline is not collapsed by compiler-inserted vmcnt drains.
#define NT48 48

__global__ __launch_bounds__(512, 2)
void gemm256_qkv(const unsigned short* __restrict__ A, const unsigned short* __restrict__ B,
                 unsigned short* __restrict__ qh, unsigned short* __restrict__ kh,
                 unsigned short* __restrict__ vt)
{
    __shared__ __attribute__((aligned(16))) unsigned short As[2*16384];
    __shared__ __attribute__((aligned(16))) unsigned short Bs[2*16384];

    const int tid  = threadIdx.x;
    const int wave = tid >> 6;
    const int lane = tid & 63;
    const int l15  = lane & 15;
    const int quad = lane >> 4;
    const int wr   = wave >> 2;   // 0..1  (M)
    const int wc   = wave & 3;    // 0..3  (N)

    // XCD-aware bijective swizzle: 192 blocks, 192 % 8 == 0
    const int id  = blockIdx.x;
    const int swz = (id & 7)*24 + (id >> 3);
    const int m0  = (swz & 15) * 256;   // 16 M-tiles
    const int n0  = (swz >> 4) * 256;   // 12 N-tiles

    // staging decode: LDS linear 16B chunk p -> (local row, k elem) via inverse swizzle
    int lrr[2], kel[2];
    #pragma unroll
    for (int j = 0; j < 2; ++j) {
        int p  = (j*512 + tid) * 16;            // byte within 16KB region
        int st = p >> 10;                       // subtile 0..15
        int q  = p & 1023;
        int ql = q ^ (((q >> 9) & 1) << 5);     // inverse st_16x32 (involution)
        lrr[j] = (st >> 1)*16 + (ql >> 6);      // local row 0..127
        kel[j] = (st & 1)*32 + ((ql & 63) >> 1);// k element 0..63
    }
    const int ldsc = wave*64*8;  // wave-uniform chunk base (ushorts); +j*4096

    auto stageA = [&](int t, int g) {
        unsigned short* dst = As + (t & 1)*16384 + g*8192;
        #pragma unroll
        for (int j = 0; j < 2; ++j) {
            int grow = (lrr[j] >> 6)*128 + g*64 + (lrr[j] & 63);
            async16(A + (size_t)(m0 + grow)*K3C + t*64 + kel[j], dst + j*4096 + ldsc);
        }
    };
    auto stageB = [&](int t, int g) {
        unsigned short* dst = Bs + (t & 1)*16384 + g*8192;
        #pragma unroll
        for (int j = 0; j < 2; ++j) {
            int grow = (lrr[j] >> 5)*64 + g*32 + (lrr[j] & 31);
            async16(B + (size_t)(n0 + grow)*K3C + t*64 + kel[j], dst + j*4096 + ldsc);
        }
    };

    // per-lane swizzled ds_read byte offset within a subtile row-block
    const unsigned lanebyte = (unsigned)((l15*64 + quad*16) ^ ((l15 & 8) << 2));
    // 32-bit LDS addresses (generic pointer low 32 bits = LDS byte offset)
    const unsigned aAddr = (unsigned)(uintptr_t)&As[0] + lanebyte + (unsigned)(wr*8192);
    const unsigned bAddr = (unsigned)(uintptr_t)&Bs[0] + lanebyte + (unsigned)(wc*4096);

    f32x4 acc[8][4] = {};

    // prologue: tile0 fully + tile1 {A_L,B_L,A_H}; B_H(1) is issued in t=0 P1.
    stageA(0, 0); stageB(0, 0); stageA(0, 1); stageB(0, 1);
    stageA(1, 0); stageB(1, 0); stageA(1, 1);
    asm volatile("s_waitcnt vmcnt(6)" ::: "memory");   // tile0's 8 loads landed
    __builtin_amdgcn_s_barrier();

    for (int tt = 0; tt < NT48; tt += 2) {
        #pragma unroll
        for (int hb = 0; hb < 2; ++hb) {
            const int t = tt + hb;                       // t&1 == hb
            uint4 ar[4][2], bl[2][2], bh[2][2];

            // ---- P1: ds-read A_L + B_L | stage B_H(t+1) | MFMA (mi 0-3, ni 0-1)
            #pragma unroll
            for (int mi = 0; mi < 4; ++mi)
                #pragma unroll
                for (int kc = 0; kc < 2; ++kc)
                    dsr(ar[mi][kc], aAddr, hb*32768 + (mi*2 + kc)*1024);
            #pragma unroll
            for (int ni = 0; ni < 2; ++ni)
                #pragma unroll
                for (int kc = 0; kc < 2; ++kc)
                    dsr(bl[ni][kc], bAddr, hb*32768 + (ni*2 + kc)*1024);
            if (t + 1 < NT48) stageB(t + 1, 1);
            __builtin_amdgcn_s_barrier();
            asm volatile("s_waitcnt lgkmcnt(0)" ::: "memory");
            __builtin_amdgcn_sched_barrier(0);
            __builtin_amdgcn_s_setprio(1);
            #pragma unroll
            for (int mi = 0; mi < 4; ++mi)
                #pragma unroll
                for (int ni = 0; ni < 2; ++ni)
                    #pragma unroll
                    for (int kc = 0; kc < 2; ++kc)
                        acc[mi][ni] = __builtin_amdgcn_mfma_f32_16x16x32_bf16(
                            frag(ar[mi][kc]), frag(bl[ni][kc]), acc[mi][ni], 0, 0, 0);
            __builtin_amdgcn_s_setprio(0);
            __builtin_amdgcn_s_barrier();

            // ---- P2: ds-read B_H | stage A_L(t+2) | MFMA (mi 0-3, ni 2-3)
            #pragma unroll
            for (int ni = 0; ni < 2; ++ni)
                #pragma unroll
                for (int kc = 0; kc < 2; ++kc)
                    dsr(bh[ni][kc], bAddr, hb*32768 + 16384 + (ni*2 + kc)*1024);
            if (t + 2 < NT48) stageA(t + 2, 0);
            __builtin_amdgcn_s_barrier();
            asm volatile("s_waitcnt lgkmcnt(0)" ::: "memory");
            __builtin_amdgcn_sched_barrier(0);
            __builtin_amdgcn_s_setprio(1);
            #pragma unroll
            for (int mi = 0; mi < 4; ++mi)
                #pragma unroll
                for (int ni = 0; ni < 2; ++ni)
                    #pragma unroll
                    for (int kc = 0; kc < 2; ++kc)
                        acc[mi][ni+2] = __builtin_amdgcn_mfma_f32_16x16x32_bf16(
                            frag(ar[mi][kc]), frag(bh[ni][kc]), acc[mi][ni+2], 0, 0, 0);
            __builtin_amdgcn_s_setprio(0);
            __builtin_amdgcn_s_barrier();

            // ---- P3: ds-read A_H | stage B_L(t+2) | MFMA (mi 4-7, ni 0-1)
            #pragma unroll
            for (int mi = 0; mi < 4; ++mi)
                #pragma unroll
                for (int kc = 0; kc < 2; ++kc)
                    dsr(ar[mi][kc], aAddr, hb*32768 + 16384 + (mi*2 + kc)*1024);
            if (t + 2 < NT48) stageB(t + 2, 0);
            __builtin_amdgcn_s_barrier();
            asm volatile("s_waitcnt lgkmcnt(0)" ::: "memory");
            __builtin_amdgcn_sched_barrier(0);
            __builtin_amdgcn_s_setprio(1);
            #pragma unroll
            for (int mi = 0; mi < 4; ++mi)
                #pragma unroll
                for (int ni = 0; ni < 2; ++ni)
                    #pragma unroll
                    for (int kc = 0; kc < 2; ++kc)
                        acc[mi+4][ni] = __builtin_amdgcn_mfma_f32_16x16x32_bf16(
                            frag(ar[mi][kc]), frag(bl[ni][kc]), acc[mi+4][ni], 0, 0, 0);
            __builtin_amdgcn_s_setprio(0);
            __builtin_amdgcn_s_barrier();

            // ---- P4: stage A_H(t+2) | counted vmcnt | MFMA (mi 4-7, ni 2-3)
            if (t + 2 < NT48) stageA(t + 2, 1);
            if (t + 2 < NT48)      { asm volatile("s_waitcnt vmcnt(6)" ::: "memory"); }
            else if (t + 1 < NT48) { asm volatile("s_waitcnt vmcnt(0)" ::: "memory"); }
            __builtin_amdgcn_s_barrier();
            __builtin_amdgcn_s_setprio(1);
            #pragma unroll
            for (int mi = 0; mi < 4; ++mi)
                #pragma unroll
                for (int ni = 0; ni < 2; ++ni)
                    #pragma unroll
                    for (int kc = 0; kc < 2; ++kc)
                        acc[mi+4][ni+2] = __builtin_amdgcn_mfma_f32_16x16x32_bf16(
                            frag(ar[mi][kc]), frag(bh[ni][kc]), acc[mi+4][ni+2], 0, 0, 0);
            __builtin_amdgcn_s_setprio(0);
            __builtin_amdgcn_s_barrier();
        }
    }

    // epilogue: route into qh (scaled), kh, vt (transposed) — same mapping as before
    #pragma unroll
    for (int mi = 0; mi < 8; ++mi) {
        const int row0 = m0 + wr*128 + mi*16 + quad*4;
        const int b  = row0 >> 11;
        const int nq = row0 & 2047;
        #pragma unroll
        for (int ni = 0; ni < 4; ++ni) {
            const int col   = n0 + wc*64 + ni*16 + l15;
            const int which = col >> 10;
            const int h     = (col >> 6) & 15;
            const int d     = col & 63;
            const int bh_   = b*HEADS + h;
            if (which == 2) {
                ushort4 pv;
                pv.x = f2bf(acc[mi][ni][0]);
                pv.y = f2bf(acc[mi][ni][1]);
                pv.z = f2bf(acc[mi][ni][2]);
                pv.w = f2bf(acc[mi][ni][3]);
                *(ushort4*)&vt[((size_t)bh_*HD + d)*SEQ + nq] = pv;
            } else {
                unsigned short* dst = (which == 0) ? qh : kh;
                float sc = (which == 0) ? QSCALE : 1.0f;
                #pragma unroll
                for (int r = 0; r < 4; ++r)
                    dst[((size_t)bh_*SEQ + nq + r)*HD + d] = f2bf(acc[mi][ni][r] * sc);
            }
        }
    }
}

// ---------------- flash attention: 32 q/wave + async double-buffered K/V ----------------
__global__ __launch_bounds__(256, 2)
void attention(const unsigned short* __restrict__ qh, const unsigned short* __restrict__ kh,
               const unsigned short* __restrict__ vt, unsigned short* __restrict__ xb)
{
    const int qt = blockIdx.x;          // 0..15 (tiles of 128 q)
    const int h  = blockIdx.y;
    const int b  = blockIdx.z;
    const int bh = b*HEADS + h;
    const int tid  = threadIdx.x;
    const int wave = tid >> 6;
    const int lane = tid & 63;
    const int l15  = lane & 15;
    const int quad = lane >> 4;

    __shared__ __attribute__((aligned(16))) unsigned short Ks[2][64*64];
    __shared__ __attribute__((aligned(16))) unsigned short Vs[2][64*64];
    __shared__ __attribute__((aligned(16))) unsigned short Ps[4][2*16*72];

    const unsigned short* Qp = qh + ((size_t)bh*SEQ + qt*128 + wave*32)*HD;
    const unsigned short* Kp = kh + (size_t)bh*SEQ*HD;
    const unsigned short* Vp = vt + (size_t)bh*HD*SEQ;

    auto stage = [&](int kt, int bufI) {
        #pragma unroll
        for (int t = 0; t < 2; ++t) {
            int c  = t*256 + wave*64 + lane;   // chunk index 0..511
            int r  = c >> 3;
            int cc = (c & 7) ^ (r & 7);
            async16(Kp + (size_t)(kt*64 + r)*HD + cc*8,
                    &Ks[bufI][(t*256 + wave*64)*8]);
            async16(Vp + (size_t)r*SEQ + kt*64 + cc*8,
                    &Vs[bufI][(t*256 + wave*64)*8]);
        }
    };

    stage(0, 0);

    uint4 qf[2][2];
    #pragma unroll
    for (int g = 0; g < 2; ++g) {
        qf[g][0] = *(const uint4*)(Qp + (size_t)(g*16 + l15)*HD + quad*8);
        qf[g][1] = *(const uint4*)(Qp + (size_t)(g*16 + l15)*HD + 32 + quad*8);
    }

    f32x4 o[2][4] = {};
    float m_s[2] = {-INFINITY, -INFINITY};
    float l_s[2] = {0.f, 0.f};

    unsigned short* Pw = Ps[wave];
    const int x7 = l15 & 7;

    for (int kt = 0; kt < SEQ/64; ++kt) {
        stage((kt + 1) & 31, (kt + 1) & 1);
        asm volatile("s_waitcnt vmcnt(4)" ::: "memory");
        asm volatile("s_barrier" ::: "memory");

        const unsigned short* Kb = Ks[kt & 1];
        const unsigned short* Vb = Vs[kt & 1];

        f32x4 s[2][4];
        #pragma unroll
        for (int st = 0; st < 4; ++st) {
            int rb = st*16 + l15;
            uint4 kf0 = *(const uint4*)&Kb[(rb*8 + (quad ^ x7))*8];
            uint4 kf1 = *(const uint4*)&Kb[(rb*8 + ((4 + quad) ^ x7))*8];
            #pragma unroll
            for (int g = 0; g < 2; ++g) {
                f32x4 z = {};
                z = __builtin_amdgcn_mfma_f32_16x16x32_bf16(frag(kf0), frag(qf[g][0]), z, 0, 0, 0);
                z = __builtin_amdgcn_mfma_f32_16x16x32_bf16(frag(kf1), frag(qf[g][1]), z, 0, 0, 0);
                s[g][st] = z;
            }
        }

        #pragma unroll
        for (int g = 0; g < 2; ++g) {
            float mloc = s[g][0][0];
            #pragma unroll
            for (int st = 0; st < 4; ++st)
                #pragma unroll
                for (int r = 0; r < 4; ++r)
                    mloc = fmaxf(mloc, s[g][st][r]);
            mloc = fmaxf(mloc, __shfl_xor(mloc, 16));
            mloc = fmaxf(mloc, __shfl_xor(mloc, 32));

            float mn = fmaxf(m_s[g], mloc);
            float al = __builtin_amdgcn_exp2f(m_s[g] - mn);
            m_s[g] = mn;

            float rs = 0.f;
            float p[4][4];
            #pragma unroll
            for (int st = 0; st < 4; ++st)
                #pragma unroll
                for (int r = 0; r < 4; ++r) {
                    p[st][r] = __builtin_amdgcn_exp2f(s[g][st][r] - mn);
                    rs += p[st][r];
                }
            rs += __shfl_xor(rs, 16);
            rs += __shfl_xor(rs, 32);
            l_s[g] = al*l_s[g] + rs;

            #pragma unroll
            for (int st = 0; st < 4; ++st)
                #pragma unroll
                for (int r = 0; r < 4; ++r)
                    o[g][st][r] *= al;

            #pragma unroll
            for (int st = 0; st < 4; ++st) {
                uint2 pk;
                pk.x = pack2bf(p[st][0], p[st][1]);
                pk.y = pack2bf(p[st][2], p[st][3]);
                *(uint2*)&Pw[g*1152 + l15*72 + st*16 + quad*4] = pk;
            }
        }
        asm volatile("s_waitcnt lgkmcnt(0)" ::: "memory");

        uint4 pB[2][2];
        #pragma unroll
        for (int g = 0; g < 2; ++g) {
            pB[g][0] = *(const uint4*)&Pw[g*1152 + l15*72 + quad*8];
            pB[g][1] = *(const uint4*)&Pw[g*1152 + l15*72 + 32 + quad*8];
        }

        #pragma unroll
        for (int st = 0; st < 4; ++st) {
            int rb = st*16 + l15;
            uint4 vf0 = *(const uint4*)&Vb[(rb*8 + (quad ^ x7))*8];
            uint4 vf1 = *(const uint4*)&Vb[(rb*8 + ((4 + quad) ^ x7))*8];
            #pragma unroll
            for (int g = 0; g < 2; ++g) {
                o[g][st] = __builtin_amdgcn_mfma_f32_16x16x32_bf16(frag(vf0), frag(pB[g][0]), o[g][st], 0, 0, 0);
                o[g][st] = __builtin_amdgcn_mfma_f32_16x16x32_bf16(frag(vf1), frag(pB[g][1]), o[g][st], 0, 0, 0);
            }
        }

        asm volatile("s_barrier" ::: "memory");
    }

    #pragma unroll
    for (int g = 0; g < 2; ++g) {
        float inv = 1.0f / l_s[g];
        #pragma unroll
        for (int st = 0; st < 4; ++st) {
            uint2 pk;
            pk.x = pack2bf(o[g][st][0]*inv, o[g][st][1]*inv);
            pk.y = pack2bf(o[g][st][2]*inv, o[g][st][3]*inv);
            *(uint2*)&Pw[g*1152 + l15*72 + st*16 + quad*4] = pk;
        }
    }
    asm volatile("s_waitcnt lgkmcnt(0)" ::: "memory");

    const int qr = lane >> 2;          // 0..15
    const int dd = (lane & 3) * 16;    // 0,16,32,48
    #pragma unroll
    for (int g = 0; g < 2; ++g) {
        uint4 oa = *(const uint4*)&Pw[g*1152 + qr*72 + dd];
        uint4 ob = *(const uint4*)&Pw[g*1152 + qr*72 + dd + 8];
        const int mrow = b*SEQ + qt*128 + wave*32 + g*16 + qr;
        *(uint4*)&xb[(size_t)mrow*CDIM + h*HD + dd]     = oa;
        *(uint4*)&xb[(size_t)mrow*CDIM + h*HD + dd + 8] = ob;
    }
}

extern "C" void kernel_launch(void* const* d_in, const int* in_sizes, int n_in,
                              void* d_out, int out_size, void* d_ws, size_t ws_size,
                              hipStream_t stream)
{
    const float* q  = (const float*)d_in[0];
    const float* k  = (const float*)d_in[1];
    const float* v  = (const float*)d_in[2];
    const float* Wq = (const float*)d_in[3];
    const float* Wp = (const float*)d_in[4];
    const float* bp = (const float*)d_in[5];
    float* out = (float*)d_out;

    char* p = (char*)d_ws;
    auto carve = [&](size_t bytes) { char* r = p; p += (bytes + 255) & ~(size_t)255; return r; };
    unsigned short* Abuf   = (unsigned short*)carve((size_t)MROWS*K3C*2);
    unsigned short* Wqkvb  = (unsigned short*)carve((size_t)K3C*K3C*2);
    unsigned short* Wprojb = (unsigned short*)carve((size_t)CDIM*CDIM*2);
    unsigned short* qhb    = (unsigned short*)carve((size_t)BATCH*HEADS*SEQ*HD*2);
    unsigned short* khb    = (unsigned short*)carve((size_t)BATCH*HEADS*SEQ*HD*2);
    unsigned short* vtb    = (unsigned short*)carve((size_t)BATCH*HEADS*SEQ*HD*2);
    unsigned short* xbuf   = (unsigned short*)carve((size_t)MROWS*CDIM*2);

    cast_all<<<MROWS + 9216 + 1024, 256, 0, stream>>>(q, k, v, Wq, Wp, Abuf, Wqkvb, Wprojb);

    gemm256_qkv<<<dim3(192), 512, 0, stream>>>(Abuf, Wqkvb, qhb, khb, vtb);

    attention<<<dim3(SEQ/128, HEADS, BATCH), 256, 0, stream>>>(qhb, khb, vtb, xbuf);

    gemm_bt<1><<<dim3(MROWS/128, CDIM/128), 256, 0, stream>>>(
        xbuf, Wprojb, MROWS, CDIM, CDIM, nullptr, nullptr, nullptr, bp, out);
}

// Round 3
// 300.375 us; speedup vs baseline: 1.0160x; 1.0006x over previous
//
#include <hip/hip_runtime.h>
#include <hip/hip_bf16.h>
#include <stdint.h>

#define HEADS 16
#define HD 64
#define SEQ 2048
#define BATCH 2
#define CDIM 1024
#define MROWS (BATCH*SEQ)   // 4096
#define K3C (3*CDIM)        // 3072
// Q prescale: attn scale 1/8 times log2(e), so softmax uses exp2 directly
#define QSCALE 0.1803368801111244f

typedef __bf16 bf16x8 __attribute__((ext_vector_type(8)));
typedef float  f32x4  __attribute__((ext_vector_type(4)));

__device__ __forceinline__ unsigned short f2bf(float f) {
    __hip_bfloat16 h = __float2bfloat16(f);
    return __builtin_bit_cast(unsigned short, h);
}
__device__ __forceinline__ unsigned int pack2bf(float a, float b) {
    return (unsigned int)f2bf(a) | ((unsigned int)f2bf(b) << 16);
}
__device__ __forceinline__ bf16x8 frag(uint4 u) { return __builtin_bit_cast(bf16x8, u); }

// async global->LDS: per-lane global gather -> contiguous LDS (base + lane*16)
__device__ __forceinline__ void async16(const unsigned short* g, unsigned short* lds) {
    __builtin_amdgcn_global_load_lds(
        (const __attribute__((address_space(1))) unsigned int*)g,
        (__attribute__((address_space(3))) unsigned int*)lds, 16, 0, 0);
}

// inline-asm ds_read_b128 hidden from the LDS-DMA hazard pass (keeps the
// counted-vmcnt pipeline); must be followed by lgkmcnt(0)+sched_barrier(0)
// before consuming MFMAs (rule #18).
__device__ __forceinline__ void dsr(uint4& d, unsigned addr, unsigned imm) {
    asm volatile("ds_read_b128 %0, %1 offset:%c2" : "=v"(d) : "v"(addr), "i"(imm));
}

// ---------------- fused cast kernel ----------------
__global__ void cast_all(const float* __restrict__ q, const float* __restrict__ k,
                         const float* __restrict__ v, const float* __restrict__ Wq,
                         const float* __restrict__ Wp,
                         unsigned short* __restrict__ A, unsigned short* __restrict__ Wqb,
                         unsigned short* __restrict__ Wpb)
{
    const int bid = blockIdx.x;
    const int t = threadIdx.x;
    if (bid < MROWS) {
        const float* srcs[3] = {q, k, v};
        #pragma unroll
        for (int i = 0; i < 3; ++i) {
            float4 f = *(const float4*)(srcs[i] + (size_t)bid*CDIM + t*4);
            ushort4 s;
            s.x = f2bf(f.x); s.y = f2bf(f.y); s.z = f2bf(f.z); s.w = f2bf(f.w);
            *(ushort4*)(A + (size_t)bid*K3C + i*CDIM + t*4) = s;
        }
    } else if (bid < MROWS + 9216) {
        int idx = (bid - MROWS)*256 + t;
        float4 f = ((const float4*)Wq)[idx];
        ushort4 s;
        s.x = f2bf(f.x); s.y = f2bf(f.y); s.z = f2bf(f.z); s.w = f2bf(f.w);
        ((ushort4*)Wqb)[idx] = s;
    } else {
        int idx = (bid - MROWS - 9216)*256 + t;
        float4 f = ((const float4*)Wp)[idx];
        ushort4 s;
        s.x = f2bf(f.x); s.y = f2bf(f.y); s.z = f2bf(f.z); s.w = f2bf(f.w);
        ((ushort4*)Wpb)[idx] = s;
    }
}

// ---------------- m97-style bf16 GEMM (BK=32) — kept for the proj GEMM ----------------
template<int EPI>
__global__ __launch_bounds__(256, 2)
void gemm_bt(const unsigned short* __restrict__ A, const unsigned short* __restrict__ B,
             int M, int N, int K,
             unsigned short* __restrict__ qh, unsigned short* __restrict__ kh,
             unsigned short* __restrict__ vt,
             const float* __restrict__ bias, float* __restrict__ out)
{
    __shared__ __attribute__((aligned(16))) unsigned short As[128*32];
    __shared__ __attribute__((aligned(16))) unsigned short Bs[128*32];
    const int tid  = threadIdx.x;
    const int wave = tid >> 6;
    const int lane = tid & 63;
    const int l15  = lane & 15;
    const int quad = lane >> 4;
    const int wm = (wave >> 1) * 64;
    const int wn = (wave & 1) * 64;
    const int m0 = blockIdx.x * 128;
    const int n0 = blockIdx.y * 128;

    f32x4 acc[4][4] = {};

    const int srow = tid >> 2;
    const int sc8  = (tid & 3) * 8;

    for (int k0 = 0; k0 < K; k0 += 32) {
        #pragma unroll
        for (int t = 0; t < 2; ++t) {
            int row = t*64 + srow;
            const unsigned short* ga = A + (size_t)(m0 + row)*K + k0 + sc8;
            const unsigned short* gb = B + (size_t)(n0 + row)*K + k0 + sc8;
            async16(ga, &As[(t*256 + wave*64)*8]);
            async16(gb, &Bs[(t*256 + wave*64)*8]);
        }
        __syncthreads();
        uint4 af[4], bfv[4];
        #pragma unroll
        for (int i = 0; i < 4; ++i) {
            af[i]  = *(const uint4*)&As[(wm + i*16 + l15)*32 + quad*8];
            bfv[i] = *(const uint4*)&Bs[(wn + i*16 + l15)*32 + quad*8];
        }
        #pragma unroll
        for (int mi = 0; mi < 4; ++mi)
            #pragma unroll
            for (int ni = 0; ni < 4; ++ni)
                acc[mi][ni] = __builtin_amdgcn_mfma_f32_16x16x32_bf16(
                    frag(af[mi]), frag(bfv[ni]), acc[mi][ni], 0, 0, 0);
        __syncthreads();
    }

    if constexpr (EPI == 0) {
        #pragma unroll
        for (int mi = 0; mi < 4; ++mi) {
            int row0 = m0 + wm + mi*16 + quad*4;
            int b  = row0 >> 11;
            int nq = row0 & 2047;
            #pragma unroll
            for (int ni = 0; ni < 4; ++ni) {
                int col   = n0 + wn + ni*16 + l15;
                int which = col >> 10;
                int h     = (col >> 6) & 15;
                int d     = col & 63;
                int bh    = b*HEADS + h;
                if (which == 2) {
                    ushort4 pv;
                    pv.x = f2bf(acc[mi][ni][0]);
                    pv.y = f2bf(acc[mi][ni][1]);
                    pv.z = f2bf(acc[mi][ni][2]);
                    pv.w = f2bf(acc[mi][ni][3]);
                    *(ushort4*)&vt[((size_t)bh*HD + d)*SEQ + nq] = pv;
                } else {
                    unsigned short* dst = (which == 0) ? qh : kh;
                    float sc = (which == 0) ? QSCALE : 1.0f;
                    #pragma unroll
                    for (int r = 0; r < 4; ++r)
                        dst[((size_t)bh*SEQ + nq + r)*HD + d] = f2bf(acc[mi][ni][r] * sc);
                }
            }
        }
    } else {
        #pragma unroll
        for (int mi = 0; mi < 4; ++mi) {
            int row0 = m0 + wm + mi*16 + quad*4;
            #pragma unroll
            for (int ni = 0; ni < 4; ++ni) {
                int col  = n0 + wn + ni*16 + l15;
                float bv = bias[col];
                #pragma unroll
                for (int r = 0; r < 4; ++r)
                    out[(size_t)(row0 + r)*N + col] = acc[mi][ni][r] + bv;
            }
        }
    }
}

// ---------------- 256x192 4-phase bf16 GEMM for the QKV projection ----------------
// Round-3 delta: BM=256 BN=192 -> grid 16x16 = 256 blocks = 1 per CU (round 2's
// 192 blocks left 64 CUs idle).  LDS per dbuf: A 32KB + B 24KB = 112 KiB total.
// Layout: flattened [rowblock16][kc][16][32] 1KB subtiles, st_16x32 XOR swizzle
// (involution: storage uses inverse-swizzled global source, reads XOR the byte).
// Staging: 7 units (4 A + 3 B, 1 load/thread each) issued as one burst in P4,
// after the dbuf's last ds_read (P3) + barrier; single s_waitcnt vmcnt(7)/tile.
// MFMA: kc-OUTER order (acc dep distance 8/4, was 1) so the wave issues its
// cluster without dependency stalls and the matrix-pipe drain overlaps the next
// phase's ds_reads.  Phases: 16/8/16/8 MFMA (per-wave 128x48, acc[8][3]).
#define NT48 48

__global__ __launch_bounds__(512, 2)
void gemm256_qkv(const unsigned short* __restrict__ A, const unsigned short* __restrict__ B,
                 unsigned short* __restrict__ qh, unsigned short* __restrict__ kh,
                 unsigned short* __restrict__ vt)
{
    __shared__ __attribute__((aligned(16))) unsigned short As[2*16384]; // 2 x 32KB
    __shared__ __attribute__((aligned(16))) unsigned short Bs[2*12288]; // 2 x 24KB

    const int tid  = threadIdx.x;
    const int wave = tid >> 6;
    const int lane = tid & 63;
    const int l15  = lane & 15;
    const int quad = lane >> 4;
    const int wr   = wave >> 2;   // 0..1  (M: 128 rows each)
    const int wc   = wave & 3;    // 0..3  (N: 48 cols each)

    // XCD-aware bijective swizzle: 256 blocks, 256 % 8 == 0, 32 per XCD
    const int id  = blockIdx.x;
    const int swz = (id & 7)*32 + (id >> 3);
    const int m0  = (swz & 15) * 256;   // 16 M-tiles
    const int n0  = (swz >> 4) * 192;   // 16 N-tiles

    // ---- staging precompute: unit u, this thread's (global element offset, LDS dst)
    // byte P within region -> subtile st=P>>10 (rb=st>>1, kc=st&1); within subtile
    // apply involution ql = q ^ ((q>>9&1)<<5); row=ql>>6, kbyte=ql&63.
    size_t aSrc[4]; size_t bSrc[3];
    #pragma unroll
    for (int u = 0; u < 4; ++u) {
        int P  = u*8192 + tid*16;
        int st = P >> 10, q = P & 1023;
        int ql = q ^ (((q >> 9) & 1) << 5);
        int row = m0 + (st >> 1)*16 + (ql >> 6);
        int kel = (st & 1)*32 + ((ql & 63) >> 1);
        aSrc[u] = (size_t)row*K3C + kel;
    }
    #pragma unroll
    for (int u = 0; u < 3; ++u) {
        int P  = u*8192 + tid*16;
        int st = P >> 10, q = P & 1023;
        int ql = q ^ (((q >> 9) & 1) << 5);
        int row = n0 + (st >> 1)*16 + (ql >> 6);
        int kel = (st & 1)*32 + ((ql & 63) >> 1);
        bSrc[u] = (size_t)row*K3C + kel;
    }
    const int wdst = wave*512;  // shorts; per-unit dst = base + hb*region + u*4096 + wdst

    auto stage = [&](int t) {
        const int hb = t & 1;
        #pragma unroll
        for (int u = 0; u < 4; ++u)
            async16(A + aSrc[u] + t*64, As + hb*16384 + u*4096 + wdst);
        #pragma unroll
        for (int u = 0; u < 3; ++u)
            async16(B + bSrc[u] + t*64, Bs + hb*12288 + u*4096 + wdst);
    };

    // per-lane swizzled ds_read byte offset within a 1KB subtile
    const unsigned lanebyte = (unsigned)((l15*64 + quad*16) ^ ((l15 & 8) << 2));
    const unsigned aAddr = (unsigned)(uintptr_t)&As[0] + lanebyte + (unsigned)(wr*16384);
    const unsigned bAddr = (unsigned)(uintptr_t)&Bs[0] + lanebyte + (unsigned)(wc*6144);

    f32x4 acc[8][3] = {};

    // prologue: tiles 0 and 1 staged; wait tile0 (7 newest = tile1 in flight)
    stage(0); stage(1);
    asm volatile("s_waitcnt vmcnt(7)" ::: "memory");
    __builtin_amdgcn_s_barrier();

    for (int tt = 0; tt < NT48; tt += 2) {
        #pragma unroll
        for (int hb = 0; hb < 2; ++hb) {
            const int t = tt + hb;                       // t&1 == hb
            uint4 ar[4][2], bl[2][2], bh[2];

            // ---- P1: ds-read A_L (8) + B n0,n1 (4) | MFMA miL x {ni0,ni1} (16)
            #pragma unroll
            for (int mi = 0; mi < 4; ++mi)
                #pragma unroll
                for (int kc = 0; kc < 2; ++kc)
                    dsr(ar[mi][kc], aAddr, hb*32768 + mi*2048 + kc*1024);
            #pragma unroll
            for (int ni = 0; ni < 2; ++ni)
                #pragma unroll
                for (int kc = 0; kc < 2; ++kc)
                    dsr(bl[ni][kc], bAddr, hb*24576 + ni*2048 + kc*1024);
            __builtin_amdgcn_s_barrier();
            asm volatile("s_waitcnt lgkmcnt(0)" ::: "memory");
            __builtin_amdgcn_sched_barrier(0);
            __builtin_amdgcn_s_setprio(1);
            #pragma unroll
            for (int kc = 0; kc < 2; ++kc)
                #pragma unroll
                for (int mi = 0; mi < 4; ++mi)
                    #pragma unroll
                    for (int ni = 0; ni < 2; ++ni)
                        acc[mi][ni] = __builtin_amdgcn_mfma_f32_16x16x32_bf16(
                            frag(ar[mi][kc]), frag(bl[ni][kc]), acc[mi][ni], 0, 0, 0);
            __builtin_amdgcn_s_setprio(0);
            __builtin_amdgcn_s_barrier();

            // ---- P2: ds-read B n2 (2) | MFMA miL x {ni2} (8)
            #pragma unroll
            for (int kc = 0; kc < 2; ++kc)
                dsr(bh[kc], bAddr, hb*24576 + 2*2048 + kc*1024);
            __builtin_amdgcn_s_barrier();
            asm volatile("s_waitcnt lgkmcnt(0)" ::: "memory");
            __builtin_amdgcn_sched_barrier(0);
            __builtin_amdgcn_s_setprio(1);
            #pragma unroll
            for (int kc = 0; kc < 2; ++kc)
                #pragma unroll
                for (int mi = 0; mi < 4; ++mi)
                    acc[mi][2] = __builtin_amdgcn_mfma_f32_16x16x32_bf16(
                        frag(ar[mi][kc]), frag(bh[kc]), acc[mi][2], 0, 0, 0);
            __builtin_amdgcn_s_setprio(0);
            __builtin_amdgcn_s_barrier();

            // ---- P3: ds-read A_H (8, reuse ar) | MFMA miH x {ni0,ni1} (16)
            #pragma unroll
            for (int mi = 0; mi < 4; ++mi)
                #pragma unroll
                for (int kc = 0; kc < 2; ++kc)
                    dsr(ar[mi][kc], aAddr, hb*32768 + (4 + mi)*2048 + kc*1024);
            __builtin_amdgcn_s_barrier();
            asm volatile("s_waitcnt lgkmcnt(0)" ::: "memory");
            __builtin_amdgcn_sched_barrier(0);
            __builtin_amdgcn_s_setprio(1);
            #pragma unroll
            for (int kc = 0; kc < 2; ++kc)
                #pragma unroll
                for (int mi = 0; mi < 4; ++mi)
                    #pragma unroll
                    for (int ni = 0; ni < 2; ++ni)
                        acc[mi+4][ni] = __builtin_amdgcn_mfma_f32_16x16x32_bf16(
                            frag(ar[mi][kc]), frag(bl[ni][kc]), acc[mi+4][ni], 0, 0, 0);
            __builtin_amdgcn_s_setprio(0);
            __builtin_amdgcn_s_barrier();

            // ---- P4: stage burst (t+2, 7 units) | vmcnt(7) | MFMA miH x {ni2} (8)
            if (t + 2 < NT48)      { stage(t + 2);
                                     asm volatile("s_waitcnt vmcnt(7)" ::: "memory"); }
            else if (t + 1 < NT48) { asm volatile("s_waitcnt vmcnt(0)" ::: "memory"); }
            __builtin_amdgcn_s_barrier();
            __builtin_amdgcn_s_setprio(1);
            #pragma unroll
            for (int kc = 0; kc < 2; ++kc)
                #pragma unroll
                for (int mi = 0; mi < 4; ++mi)
                    acc[mi+4][2] = __builtin_amdgcn_mfma_f32_16x16x32_bf16(
                        frag(ar[mi][kc]), frag(bh[kc]), acc[mi+4][2], 0, 0, 0);
            __builtin_amdgcn_s_setprio(0);
            __builtin_amdgcn_s_barrier();
        }
    }

    // epilogue: route into qh (scaled), kh, vt (transposed); per-column decode
    #pragma unroll
    for (int mi = 0; mi < 8; ++mi) {
        const int row0 = m0 + wr*128 + mi*16 + quad*4;
        const int b  = row0 >> 11;
        const int nq = row0 & 2047;
        #pragma unroll
        for (int ni = 0; ni < 3; ++ni) {
            const int col   = n0 + wc*48 + ni*16 + l15;
            const int which = col >> 10;
            const int h     = (col >> 6) & 15;
            const int d     = col & 63;
            const int bh_   = b*HEADS + h;
            if (which == 2) {
                ushort4 pv;
                pv.x = f2bf(acc[mi][ni][0]);
                pv.y = f2bf(acc[mi][ni][1]);
                pv.z = f2bf(acc[mi][ni][2]);
                pv.w = f2bf(acc[mi][ni][3]);
                *(ushort4*)&vt[((size_t)bh_*HD + d)*SEQ + nq] = pv;
            } else {
                unsigned short* dst = (which == 0) ? qh : kh;
                float sc = (which == 0) ? QSCALE : 1.0f;
                #pragma unroll
                for (int r = 0; r < 4; ++r)
                    dst[((size_t)bh_*SEQ + nq + r)*HD + d] = f2bf(acc[mi][ni][r] * sc);
            }
        }
    }
}

// ---------------- flash attention: 32 q/wave + async double-buffered K/V ----------------
__global__ __launch_bounds__(256, 2)
void attention(const unsigned short* __restrict__ qh, const unsigned short* __restrict__ kh,
               const unsigned short* __restrict__ vt, unsigned short* __restrict__ xb)
{
    const int qt = blockIdx.x;          // 0..15 (tiles of 128 q)
    const int h  = blockIdx.y;
    const int b  = blockIdx.z;
    const int bh = b*HEADS + h;
    const int tid  = threadIdx.x;
    const int wave = tid >> 6;
    const int lane = tid & 63;
    const int l15  = lane & 15;
    const int quad = lane >> 4;

    __shared__ __attribute__((aligned(16))) unsigned short Ks[2][64*64];
    __shared__ __attribute__((aligned(16))) unsigned short Vs[2][64*64];
    __shared__ __attribute__((aligned(16))) unsigned short Ps[4][2*16*72];

    const unsigned short* Qp = qh + ((size_t)bh*SEQ + qt*128 + wave*32)*HD;
    const unsigned short* Kp = kh + (size_t)bh*SEQ*HD;
    const unsigned short* Vp = vt + (size_t)bh*HD*SEQ;

    auto stage = [&](int kt, int bufI) {
        #pragma unroll
        for (int t = 0; t < 2; ++t) {
            int c  = t*256 + wave*64 + lane;   // chunk index 0..511
            int r  = c >> 3;
            int cc = (c & 7) ^ (r & 7);
            async16(Kp + (size_t)(kt*64 + r)*HD + cc*8,
                    &Ks[bufI][(t*256 + wave*64)*8]);
            async16(Vp + (size_t)r*SEQ + kt*64 + cc*8,
                    &Vs[bufI][(t*256 + wave*64)*8]);
        }
    };

    stage(0, 0);

    uint4 qf[2][2];
    #pragma unroll
    for (int g = 0; g < 2; ++g) {
        qf[g][0] = *(const uint4*)(Qp + (size_t)(g*16 + l15)*HD + quad*8);
        qf[g][1] = *(const uint4*)(Qp + (size_t)(g*16 + l15)*HD + 32 + quad*8);
    }

    f32x4 o[2][4] = {};
    float m_s[2] = {-INFINITY, -INFINITY};
    float l_s[2] = {0.f, 0.f};

    unsigned short* Pw = Ps[wave];
    const int x7 = l15 & 7;

    for (int kt = 0; kt < SEQ/64; ++kt) {
        stage((kt + 1) & 31, (kt + 1) & 1);
        asm volatile("s_waitcnt vmcnt(4)" ::: "memory");
        asm volatile("s_barrier" ::: "memory");

        const unsigned short* Kb = Ks[kt & 1];
        const unsigned short* Vb = Vs[kt & 1];

        f32x4 s[2][4];
        #pragma unroll
        for (int st = 0; st < 4; ++st) {
            int rb = st*16 + l15;
            uint4 kf0 = *(const uint4*)&Kb[(rb*8 + (quad ^ x7))*8];
            uint4 kf1 = *(const uint4*)&Kb[(rb*8 + ((4 + quad) ^ x7))*8];
            #pragma unroll
            for (int g = 0; g < 2; ++g) {
                f32x4 z = {};
                z = __builtin_amdgcn_mfma_f32_16x16x32_bf16(frag(kf0), frag(qf[g][0]), z, 0, 0, 0);
                z = __builtin_amdgcn_mfma_f32_16x16x32_bf16(frag(kf1), frag(qf[g][1]), z, 0, 0, 0);
                s[g][st] = z;
            }
        }

        #pragma unroll
        for (int g = 0; g < 2; ++g) {
            float mloc = s[g][0][0];
            #pragma unroll
            for (int st = 0; st < 4; ++st)
                #pragma unroll
                for (int r = 0; r < 4; ++r)
                    mloc = fmaxf(mloc, s[g][st][r]);
            mloc = fmaxf(mloc, __shfl_xor(mloc, 16));
            mloc = fmaxf(mloc, __shfl_xor(mloc, 32));

            float mn = fmaxf(m_s[g], mloc);
            float al = __builtin_amdgcn_exp2f(m_s[g] - mn);
            m_s[g] = mn;

            float rs = 0.f;
            float p[4][4];
            #pragma unroll
            for (int st = 0; st < 4; ++st)
                #pragma unroll
                for (int r = 0; r < 4; ++r) {
                    p[st][r] = __builtin_amdgcn_exp2f(s[g][st][r] - mn);
                    rs += p[st][r];
                }
            rs += __shfl_xor(rs, 16);
            rs += __shfl_xor(rs, 32);
            l_s[g] = al*l_s[g] + rs;

            #pragma unroll
            for (int st = 0; st < 4; ++st)
                #pragma unroll
                for (int r = 0; r < 4; ++r)
                    o[g][st][r] *= al;

            #pragma unroll
            for (int st = 0; st < 4; ++st) {
                uint2 pk;
                pk.x = pack2bf(p[st][0], p[st][1]);
                pk.y = pack2bf(p[st][2], p[st][3]);
                *(uint2*)&Pw[g*1152 + l15*72 + st*16 + quad*4] = pk;
            }
        }
        asm volatile("s_waitcnt lgkmcnt(0)" ::: "memory");

        uint4 pB[2][2];
        #pragma unroll
        for (int g = 0; g < 2; ++g) {
            pB[g][0] = *(const uint4*)&Pw[g*1152 + l15*72 + quad*8];
            pB[g][1] = *(const uint4*)&Pw[g*1152 + l15*72 + 32 + quad*8];
        }

        #pragma unroll
        for (int st = 0; st < 4; ++st) {
            int rb = st*16 + l15;
            uint4 vf0 = *(const uint4*)&Vb[(rb*8 + (quad ^ x7))*8];
            uint4 vf1 = *(const uint4*)&Vb[(rb*8 + ((4 + quad) ^ x7))*8];
            #pragma unroll
            for (int g = 0; g < 2; ++g) {
                o[g][st] = __builtin_amdgcn_mfma_f32_16x16x32_bf16(frag(vf0), frag(pB[g][0]), o[g][st], 0, 0, 0);
                o[g][st] = __builtin_amdgcn_mfma_f32_16x16x32_bf16(frag(vf1), frag(pB[g][1]), o[g][st], 0, 0, 0);
            }
        }

        asm volatile("s_barrier" ::: "memory");
    }

    #pragma unroll
    for (int g = 0; g < 2; ++g) {
        float inv = 1.0f / l_s[g];
        #pragma unroll
        for (int st = 0; st < 4; ++st) {
            uint2 pk;
            pk.x = pack2bf(o[g][st][0]*inv, o[g][st][1]*inv);
            pk.y = pack2bf(o[g][st][2]*inv, o[g][st][3]*inv);
            *(uint2*)&Pw[g*1152 + l15*72 + st*16 + quad*4] = pk;
        }
    }
    asm volatile("s_waitcnt lgkmcnt(0)" ::: "memory");

    const int qr = lane >> 2;          // 0..15
    const int dd = (lane & 3) * 16;    // 0,16,32,48
    #pragma unroll
    for (int g = 0; g < 2; ++g) {
        uint4 oa = *(const uint4*)&Pw[g*1152 + qr*72 + dd];
        uint4 ob = *(const uint4*)&Pw[g*1152 + qr*72 + dd + 8];
        const int mrow = b*SEQ + qt*128 + wave*32 + g*16 + qr;
        *(uint4*)&xb[(size_t)mrow*CDIM + h*HD + dd]     = oa;
        *(uint4*)&xb[(size_t)mrow*CDIM + h*HD + dd + 8] = ob;
    }
}

extern "C" void kernel_launch(void* const* d_in, const int* in_sizes, int n_in,
                              void* d_out, int out_size, void* d_ws, size_t ws_size,
                              hipStream_t stream)
{
    const float* q  = (const float*)d_in[0];
    const float* k  = (const float*)d_in[1];
    const float* v  = (const float*)d_in[2];
    const float* Wq = (const float*)d_in[3];
    const float* Wp = (const float*)d_in[4];
    const float* bp = (const float*)d_in[5];
    float* out = (float*)d_out;

    char* p = (char*)d_ws;
    auto carve = [&](size_t bytes) { char* r = p; p += (bytes + 255) & ~(size_t)255; return r; };
    unsigned short* Abuf   = (unsigned short*)carve((size_t)MROWS*K3C*2);
    unsigned short* Wqkvb  = (unsigned short*)carve((size_t)K3C*K3C*2);
    unsigned short* Wprojb = (unsigned short*)carve((size_t)CDIM*CDIM*2);
    unsigned short* qhb    = (unsigned short*)carve((size_t)BATCH*HEADS*SEQ*HD*2);
    unsigned short* khb    = (unsigned short*)carve((size_t)BATCH*HEADS*SEQ*HD*2);
    unsigned short* vtb    = (unsigned short*)carve((size_t)BATCH*HEADS*SEQ*HD*2);
    unsigned short* xbuf   = (unsigned short*)carve((size_t)MROWS*CDIM*2);

    cast_all<<<MROWS + 9216 + 1024, 256, 0, stream>>>(q, k, v, Wq, Wp, Abuf, Wqkvb, Wprojb);

    gemm256_qkv<<<dim3(256), 512, 0, stream>>>(Abuf, Wqkvb, qhb, khb, vtb);

    attention<<<dim3(SEQ/128, HEADS, BATCH), 256, 0, stream>>>(qhb, khb, vtb, xbuf);

    gemm_bt<1><<<dim3(MROWS/128, CDIM/128), 256, 0, stream>>>(
        xbuf, Wprojb, MROWS, CDIM, CDIM, nullptr, nullptr, nullptr, bp, out);
}

// Round 4
// 287.571 us; speedup vs baseline: 1.0612x; 1.0445x over previous
//
#include <hip/hip_runtime.h>
#include <hip/hip_bf16.h>
#include <stdint.h>

#define HEADS 16
#define HD 64
#define SEQ 2048
#define BATCH 2
#define CDIM 1024
#define MROWS (BATCH*SEQ)   // 4096
#define K3C (3*CDIM)        // 3072
// Q prescale: attn scale 1/8 times log2(e), so softmax uses exp2 directly
#define QSCALE 0.1803368801111244f

typedef __bf16 bf16x8 __attribute__((ext_vector_type(8)));
typedef float  f32x4  __attribute__((ext_vector_type(4)));

__device__ __forceinline__ unsigned short f2bf(float f) {
    __hip_bfloat16 h = __float2bfloat16(f);
    return __builtin_bit_cast(unsigned short, h);
}
__device__ __forceinline__ unsigned int pack2bf(float a, float b) {
    return (unsigned int)f2bf(a) | ((unsigned int)f2bf(b) << 16);
}
__device__ __forceinline__ bf16x8 frag(uint4 u) { return __builtin_bit_cast(bf16x8, u); }

// async global->LDS: per-lane global gather -> contiguous LDS (base + lane*16)
__device__ __forceinline__ void async16(const unsigned short* g, unsigned short* lds) {
    __builtin_amdgcn_global_load_lds(
        (const __attribute__((address_space(1))) unsigned int*)g,
        (__attribute__((address_space(3))) unsigned int*)lds, 16, 0, 0);
}

// inline-asm ds_read_b128 hidden from the LDS-DMA hazard pass (keeps the
// counted-vmcnt pipeline); must be followed by lgkmcnt(0)+sched_barrier(0)
// before consuming MFMAs (rule #18).
__device__ __forceinline__ void dsr(uint4& d, unsigned addr, unsigned imm) {
    asm volatile("ds_read_b128 %0, %1 offset:%c2" : "=v"(d) : "v"(addr), "i"(imm));
}

// ---------------- fused cast kernel ----------------
__global__ void cast_all(const float* __restrict__ q, const float* __restrict__ k,
                         const float* __restrict__ v, const float* __restrict__ Wq,
                         const float* __restrict__ Wp,
                         unsigned short* __restrict__ A, unsigned short* __restrict__ Wqb,
                         unsigned short* __restrict__ Wpb)
{
    const int bid = blockIdx.x;
    const int t = threadIdx.x;
    if (bid < MROWS) {
        const float* srcs[3] = {q, k, v};
        #pragma unroll
        for (int i = 0; i < 3; ++i) {
            float4 f = *(const float4*)(srcs[i] + (size_t)bid*CDIM + t*4);
            ushort4 s;
            s.x = f2bf(f.x); s.y = f2bf(f.y); s.z = f2bf(f.z); s.w = f2bf(f.w);
            *(ushort4*)(A + (size_t)bid*K3C + i*CDIM + t*4) = s;
        }
    } else if (bid < MROWS + 9216) {
        int idx = (bid - MROWS)*256 + t;
        float4 f = ((const float4*)Wq)[idx];
        ushort4 s;
        s.x = f2bf(f.x); s.y = f2bf(f.y); s.z = f2bf(f.z); s.w = f2bf(f.w);
        ((ushort4*)Wqb)[idx] = s;
    } else {
        int idx = (bid - MROWS - 9216)*256 + t;
        float4 f = ((const float4*)Wp)[idx];
        ushort4 s;
        s.x = f2bf(f.x); s.y = f2bf(f.y); s.z = f2bf(f.z); s.w = f2bf(f.w);
        ((ushort4*)Wpb)[idx] = s;
    }
}

// ---------------- m97-style bf16 GEMM (BK=32) — kept for the proj GEMM ----------------
template<int EPI>
__global__ __launch_bounds__(256, 2)
void gemm_bt(const unsigned short* __restrict__ A, const unsigned short* __restrict__ B,
             int M, int N, int K,
             unsigned short* __restrict__ qh, unsigned short* __restrict__ kh,
             unsigned short* __restrict__ vt,
             const float* __restrict__ bias, float* __restrict__ out)
{
    __shared__ __attribute__((aligned(16))) unsigned short As[128*32];
    __shared__ __attribute__((aligned(16))) unsigned short Bs[128*32];
    const int tid  = threadIdx.x;
    const int wave = tid >> 6;
    const int lane = tid & 63;
    const int l15  = lane & 15;
    const int quad = lane >> 4;
    const int wm = (wave >> 1) * 64;
    const int wn = (wave & 1) * 64;
    const int m0 = blockIdx.x * 128;
    const int n0 = blockIdx.y * 128;

    f32x4 acc[4][4] = {};

    const int srow = tid >> 2;
    const int sc8  = (tid & 3) * 8;

    for (int k0 = 0; k0 < K; k0 += 32) {
        #pragma unroll
        for (int t = 0; t < 2; ++t) {
            int row = t*64 + srow;
            const unsigned short* ga = A + (size_t)(m0 + row)*K + k0 + sc8;
            const unsigned short* gb = B + (size_t)(n0 + row)*K + k0 + sc8;
            async16(ga, &As[(t*256 + wave*64)*8]);
            async16(gb, &Bs[(t*256 + wave*64)*8]);
        }
        __syncthreads();
        uint4 af[4], bfv[4];
        #pragma unroll
        for (int i = 0; i < 4; ++i) {
            af[i]  = *(const uint4*)&As[(wm + i*16 + l15)*32 + quad*8];
            bfv[i] = *(const uint4*)&Bs[(wn + i*16 + l15)*32 + quad*8];
        }
        #pragma unroll
        for (int mi = 0; mi < 4; ++mi)
            #pragma unroll
            for (int ni = 0; ni < 4; ++ni)
                acc[mi][ni] = __builtin_amdgcn_mfma_f32_16x16x32_bf16(
                    frag(af[mi]), frag(bfv[ni]), acc[mi][ni], 0, 0, 0);
        __syncthreads();
    }

    if constexpr (EPI == 0) {
        #pragma unroll
        for (int mi = 0; mi < 4; ++mi) {
            int row0 = m0 + wm + mi*16 + quad*4;
            int b  = row0 >> 11;
            int nq = row0 & 2047;
            #pragma unroll
            for (int ni = 0; ni < 4; ++ni) {
                int col   = n0 + wn + ni*16 + l15;
                int which = col >> 10;
                int h     = (col >> 6) & 15;
                int d     = col & 63;
                int bh    = b*HEADS + h;
                if (which == 2) {
                    ushort4 pv;
                    pv.x = f2bf(acc[mi][ni][0]);
                    pv.y = f2bf(acc[mi][ni][1]);
                    pv.z = f2bf(acc[mi][ni][2]);
                    pv.w = f2bf(acc[mi][ni][3]);
                    *(ushort4*)&vt[((size_t)bh*HD + d)*SEQ + nq] = pv;
                } else {
                    unsigned short* dst = (which == 0) ? qh : kh;
                    float sc = (which == 0) ? QSCALE : 1.0f;
                    #pragma unroll
                    for (int r = 0; r < 4; ++r)
                        dst[((size_t)bh*SEQ + nq + r)*HD + d] = f2bf(acc[mi][ni][r] * sc);
                }
            }
        }
    } else {
        #pragma unroll
        for (int mi = 0; mi < 4; ++mi) {
            int row0 = m0 + wm + mi*16 + quad*4;
            #pragma unroll
            for (int ni = 0; ni < 4; ++ni) {
                int col  = n0 + wn + ni*16 + l15;
                float bv = bias[col];
                #pragma unroll
                for (int r = 0; r < 4; ++r)
                    out[(size_t)(row0 + r)*N + col] = acc[mi][ni][r] + bv;
            }
        }
    }
}

// ---------------- 256x192 2-phase bf16 GEMM for the QKV projection ----------------
// Round-4 delta vs round 3 (geometry/mapping/staging/epilogue identical, all
// harness-verified): merge 4 phases -> 2 phases per K-tile.  Round-3 counters
// showed ~1000 cyc of fixed overhead per phase (8 barrier events/tile, lockstep
// waves, MfmaUtil 34%); halving the barrier count attacks that directly while
// keeping the counted-vmcnt(7) prefetch discipline (m218: the counted wait is
// the lever, never drain to 0 in steady state).
//   P1: ds-read A_L (8) + all B (6) | MFMA miL x ni0..2 (24)
//   P2: ds-read A_H (8) | MFMA miH x ni0..2 (24) | stage(t+2) + vmcnt(7)
// stage(t+2) overwrites buf hb after its last reads (A_H) have drained:
// mid-barrier + lgkmcnt(0) + 24-MFMA cluster separate read-completion from
// DMA-write arrival (>=200cy L2 latency).  kc-outer MFMA (acc dep distance 12).
#define NT48 48

__global__ __launch_bounds__(512, 2)
void gemm256_qkv(const unsigned short* __restrict__ A, const unsigned short* __restrict__ B,
                 unsigned short* __restrict__ qh, unsigned short* __restrict__ kh,
                 unsigned short* __restrict__ vt)
{
    __shared__ __attribute__((aligned(16))) unsigned short As[2*16384]; // 2 x 32KB
    __shared__ __attribute__((aligned(16))) unsigned short Bs[2*12288]; // 2 x 24KB

    const int tid  = threadIdx.x;
    const int wave = tid >> 6;
    const int lane = tid & 63;
    const int l15  = lane & 15;
    const int quad = lane >> 4;
    const int wr   = wave >> 2;   // 0..1  (M: 128 rows each)
    const int wc   = wave & 3;    // 0..3  (N: 48 cols each)

    // XCD-aware bijective swizzle: 256 blocks, 256 % 8 == 0, 32 per XCD
    const int id  = blockIdx.x;
    const int swz = (id & 7)*32 + (id >> 3);
    const int m0  = (swz & 15) * 256;   // 16 M-tiles
    const int n0  = (swz >> 4) * 192;   // 16 N-tiles

    // ---- staging precompute: unit u, this thread's (global element offset, LDS dst)
    // byte P within region -> subtile st=P>>10 (rb=st>>1, kc=st&1); within subtile
    // apply involution ql = q ^ ((q>>9&1)<<5); row=ql>>6, kbyte=ql&63.
    size_t aSrc[4]; size_t bSrc[3];
    #pragma unroll
    for (int u = 0; u < 4; ++u) {
        int P  = u*8192 + tid*16;
        int st = P >> 10, q = P & 1023;
        int ql = q ^ (((q >> 9) & 1) << 5);
        int row = m0 + (st >> 1)*16 + (ql >> 6);
        int kel = (st & 1)*32 + ((ql & 63) >> 1);
        aSrc[u] = (size_t)row*K3C + kel;
    }
    #pragma unroll
    for (int u = 0; u < 3; ++u) {
        int P  = u*8192 + tid*16;
        int st = P >> 10, q = P & 1023;
        int ql = q ^ (((q >> 9) & 1) << 5);
        int row = n0 + (st >> 1)*16 + (ql >> 6);
        int kel = (st & 1)*32 + ((ql & 63) >> 1);
        bSrc[u] = (size_t)row*K3C + kel;
    }
    const int wdst = wave*512;  // shorts; per-unit dst = base + hb*region + u*4096 + wdst

    auto stage = [&](int t) {
        const int hb = t & 1;
        #pragma unroll
        for (int u = 0; u < 4; ++u)
            async16(A + aSrc[u] + t*64, As + hb*16384 + u*4096 + wdst);
        #pragma unroll
        for (int u = 0; u < 3; ++u)
            async16(B + bSrc[u] + t*64, Bs + hb*12288 + u*4096 + wdst);
    };

    // per-lane swizzled ds_read byte offset within a 1KB subtile
    const unsigned lanebyte = (unsigned)((l15*64 + quad*16) ^ ((l15 & 8) << 2));
    const unsigned aAddr = (unsigned)(uintptr_t)&As[0] + lanebyte + (unsigned)(wr*16384);
    const unsigned bAddr = (unsigned)(uintptr_t)&Bs[0] + lanebyte + (unsigned)(wc*6144);

    f32x4 acc[8][3] = {};

    // prologue: tiles 0 and 1 staged; wait tile0 (7 newest = tile1 in flight)
    stage(0); stage(1);
    asm volatile("s_waitcnt vmcnt(7)" ::: "memory");
    __builtin_amdgcn_s_barrier();

    for (int tt = 0; tt < NT48; tt += 2) {
        #pragma unroll
        for (int hb = 0; hb < 2; ++hb) {
            const int t = tt + hb;                       // t&1 == hb
            uint4 ar[4][2], bb[3][2];

            // ---- P1: ds-read A_L (8) + B n0..n2 (6) | MFMA miL x {ni0,ni1,ni2} (24)
            #pragma unroll
            for (int mi = 0; mi < 4; ++mi)
                #pragma unroll
                for (int kc = 0; kc < 2; ++kc)
                    dsr(ar[mi][kc], aAddr, hb*32768 + mi*2048 + kc*1024);
            #pragma unroll
            for (int ni = 0; ni < 3; ++ni)
                #pragma unroll
                for (int kc = 0; kc < 2; ++kc)
                    dsr(bb[ni][kc], bAddr, hb*24576 + ni*2048 + kc*1024);
            __builtin_amdgcn_s_barrier();
            asm volatile("s_waitcnt lgkmcnt(0)" ::: "memory");
            __builtin_amdgcn_sched_barrier(0);
            __builtin_amdgcn_s_setprio(1);
            #pragma unroll
            for (int kc = 0; kc < 2; ++kc)
                #pragma unroll
                for (int mi = 0; mi < 4; ++mi)
                    #pragma unroll
                    for (int ni = 0; ni < 3; ++ni)
                        acc[mi][ni] = __builtin_amdgcn_mfma_f32_16x16x32_bf16(
                            frag(ar[mi][kc]), frag(bb[ni][kc]), acc[mi][ni], 0, 0, 0);
            __builtin_amdgcn_s_setprio(0);
            __builtin_amdgcn_s_barrier();

            // ---- P2: ds-read A_H (8, reuse ar) | MFMA miH x {ni0,ni1,ni2} (24)
            //         then stage(t+2) + counted vmcnt(7) before the end barrier
            #pragma unroll
            for (int mi = 0; mi < 4; ++mi)
                #pragma unroll
                for (int kc = 0; kc < 2; ++kc)
                    dsr(ar[mi][kc], aAddr, hb*32768 + (4 + mi)*2048 + kc*1024);
            __builtin_amdgcn_s_barrier();
            asm volatile("s_waitcnt lgkmcnt(0)" ::: "memory");
            __builtin_amdgcn_sched_barrier(0);
            __builtin_amdgcn_s_setprio(1);
            #pragma unroll
            for (int kc = 0; kc < 2; ++kc)
                #pragma unroll
                for (int mi = 0; mi < 4; ++mi)
                    #pragma unroll
                    for (int ni = 0; ni < 3; ++ni)
                        acc[mi+4][ni] = __builtin_amdgcn_mfma_f32_16x16x32_bf16(
                            frag(ar[mi][kc]), frag(bb[ni][kc]), acc[mi+4][ni], 0, 0, 0);
            __builtin_amdgcn_s_setprio(0);
            if (t + 2 < NT48)      { stage(t + 2);
                                     asm volatile("s_waitcnt vmcnt(7)" ::: "memory"); }
            else if (t + 1 < NT48) { asm volatile("s_waitcnt vmcnt(0)" ::: "memory"); }
            __builtin_amdgcn_s_barrier();
        }
    }

    // epilogue: route into qh (scaled), kh, vt (transposed); per-column decode
    #pragma unroll
    for (int mi = 0; mi < 8; ++mi) {
        const int row0 = m0 + wr*128 + mi*16 + quad*4;
        const int b  = row0 >> 11;
        const int nq = row0 & 2047;
        #pragma unroll
        for (int ni = 0; ni < 3; ++ni) {
            const int col   = n0 + wc*48 + ni*16 + l15;
            const int which = col >> 10;
            const int h     = (col >> 6) & 15;
            const int d     = col & 63;
            const int bh_   = b*HEADS + h;
            if (which == 2) {
                ushort4 pv;
                pv.x = f2bf(acc[mi][ni][0]);
                pv.y = f2bf(acc[mi][ni][1]);
                pv.z = f2bf(acc[mi][ni][2]);
                pv.w = f2bf(acc[mi][ni][3]);
                *(ushort4*)&vt[((size_t)bh_*HD + d)*SEQ + nq] = pv;
            } else {
                unsigned short* dst = (which == 0) ? qh : kh;
                float sc = (which == 0) ? QSCALE : 1.0f;
                #pragma unroll
                for (int r = 0; r < 4; ++r)
                    dst[((size_t)bh_*SEQ + nq + r)*HD + d] = f2bf(acc[mi][ni][r] * sc);
            }
        }
    }
}

// ---------------- flash attention: 32 q/wave + async double-buffered K/V ----------------
__global__ __launch_bounds__(256, 2)
void attention(const unsigned short* __restrict__ qh, const unsigned short* __restrict__ kh,
               const unsigned short* __restrict__ vt, unsigned short* __restrict__ xb)
{
    const int qt = blockIdx.x;          // 0..15 (tiles of 128 q)
    const int h  = blockIdx.y;
    const int b  = blockIdx.z;
    const int bh = b*HEADS + h;
    const int tid  = threadIdx.x;
    const int wave = tid >> 6;
    const int lane = tid & 63;
    const int l15  = lane & 15;
    const int quad = lane >> 4;

    __shared__ __attribute__((aligned(16))) unsigned short Ks[2][64*64];
    __shared__ __attribute__((aligned(16))) unsigned short Vs[2][64*64];
    __shared__ __attribute__((aligned(16))) unsigned short Ps[4][2*16*72];

    const unsigned short* Qp = qh + ((size_t)bh*SEQ + qt*128 + wave*32)*HD;
    const unsigned short* Kp = kh + (size_t)bh*SEQ*HD;
    const unsigned short* Vp = vt + (size_t)bh*HD*SEQ;

    auto stage = [&](int kt, int bufI) {
        #pragma unroll
        for (int t = 0; t < 2; ++t) {
            int c  = t*256 + wave*64 + lane;   // chunk index 0..511
            int r  = c >> 3;
            int cc = (c & 7) ^ (r & 7);
            async16(Kp + (size_t)(kt*64 + r)*HD + cc*8,
                    &Ks[bufI][(t*256 + wave*64)*8]);
            async16(Vp + (size_t)r*SEQ + kt*64 + cc*8,
                    &Vs[bufI][(t*256 + wave*64)*8]);
        }
    };

    stage(0, 0);

    uint4 qf[2][2];
    #pragma unroll
    for (int g = 0; g < 2; ++g) {
        qf[g][0] = *(const uint4*)(Qp + (size_t)(g*16 + l15)*HD + quad*8);
        qf[g][1] = *(const uint4*)(Qp + (size_t)(g*16 + l15)*HD + 32 + quad*8);
    }

    f32x4 o[2][4] = {};
    float m_s[2] = {-INFINITY, -INFINITY};
    float l_s[2] = {0.f, 0.f};

    unsigned short* Pw = Ps[wave];
    const int x7 = l15 & 7;

    for (int kt = 0; kt < SEQ/64; ++kt) {
        stage((kt + 1) & 31, (kt + 1) & 1);
        asm volatile("s_waitcnt vmcnt(4)" ::: "memory");
        asm volatile("s_barrier" ::: "memory");

        const unsigned short* Kb = Ks[kt & 1];
        const unsigned short* Vb = Vs[kt & 1];

        f32x4 s[2][4];
        #pragma unroll
        for (int st = 0; st < 4; ++st) {
            int rb = st*16 + l15;
            uint4 kf0 = *(const uint4*)&Kb[(rb*8 + (quad ^ x7))*8];
            uint4 kf1 = *(const uint4*)&Kb[(rb*8 + ((4 + quad) ^ x7))*8];
            #pragma unroll
            for (int g = 0; g < 2; ++g) {
                f32x4 z = {};
                z = __builtin_amdgcn_mfma_f32_16x16x32_bf16(frag(kf0), frag(qf[g][0]), z, 0, 0, 0);
                z = __builtin_amdgcn_mfma_f32_16x16x32_bf16(frag(kf1), frag(qf[g][1]), z, 0, 0, 0);
                s[g][st] = z;
            }
        }

        #pragma unroll
        for (int g = 0; g < 2; ++g) {
            float mloc = s[g][0][0];
            #pragma unroll
            for (int st = 0; st < 4; ++st)
                #pragma unroll
                for (int r = 0; r < 4; ++r)
                    mloc = fmaxf(mloc, s[g][st][r]);
            mloc = fmaxf(mloc, __shfl_xor(mloc, 16));
            mloc = fmaxf(mloc, __shfl_xor(mloc, 32));

            float mn = fmaxf(m_s[g], mloc);
            float al = __builtin_amdgcn_exp2f(m_s[g] - mn);
            m_s[g] = mn;

            float rs = 0.f;
            float p[4][4];
            #pragma unroll
            for (int st = 0; st < 4; ++st)
                #pragma unroll
                for (int r = 0; r < 4; ++r) {
                    p[st][r] = __builtin_amdgcn_exp2f(s[g][st][r] - mn);
                    rs += p[st][r];
                }
            rs += __shfl_xor(rs, 16);
            rs += __shfl_xor(rs, 32);
            l_s[g] = al*l_s[g] + rs;

            #pragma unroll
            for (int st = 0; st < 4; ++st)
                #pragma unroll
                for (int r = 0; r < 4; ++r)
                    o[g][st][r] *= al;

            #pragma unroll
            for (int st = 0; st < 4; ++st) {
                uint2 pk;
                pk.x = pack2bf(p[st][0], p[st][1]);
                pk.y = pack2bf(p[st][2], p[st][3]);
                *(uint2*)&Pw[g*1152 + l15*72 + st*16 + quad*4] = pk;
            }
        }
        asm volatile("s_waitcnt lgkmcnt(0)" ::: "memory");

        uint4 pB[2][2];
        #pragma unroll
        for (int g = 0; g < 2; ++g) {
            pB[g][0] = *(const uint4*)&Pw[g*1152 + l15*72 + quad*8];
            pB[g][1] = *(const uint4*)&Pw[g*1152 + l15*72 + 32 + quad*8];
        }

        #pragma unroll
        for (int st = 0; st < 4; ++st) {
            int rb = st*16 + l15;
            uint4 vf0 = *(const uint4*)&Vb[(rb*8 + (quad ^ x7))*8];
            uint4 vf1 = *(const uint4*)&Vb[(rb*8 + ((4 + quad) ^ x7))*8];
            #pragma unroll
            for (int g = 0; g < 2; ++g) {
                o[g][st] = __builtin_amdgcn_mfma_f32_16x16x32_bf16(frag(vf0), frag(pB[g][0]), o[g][st], 0, 0, 0);
                o[g][st] = __builtin_amdgcn_mfma_f32_16x16x32_bf16(frag(vf1), frag(pB[g][1]), o[g][st], 0, 0, 0);
            }
        }

        asm volatile("s_barrier" ::: "memory");
    }

    #pragma unroll
    for (int g = 0; g < 2; ++g) {
        float inv = 1.0f / l_s[g];
        #pragma unroll
        for (int st = 0; st < 4; ++st) {
            uint2 pk;
            pk.x = pack2bf(o[g][st][0]*inv, o[g][st][1]*inv);
            pk.y = pack2bf(o[g][st][2]*inv, o[g][st][3]*inv);
            *(uint2*)&Pw[g*1152 + l15*72 + st*16 + quad*4] = pk;
        }
    }
    asm volatile("s_waitcnt lgkmcnt(0)" ::: "memory");

    const int qr = lane >> 2;          // 0..15
    const int dd = (lane & 3) * 16;    // 0,16,32,48
    #pragma unroll
    for (int g = 0; g < 2; ++g) {
        uint4 oa = *(const uint4*)&Pw[g*1152 + qr*72 + dd];
        uint4 ob = *(const uint4*)&Pw[g*1152 + qr*72 + dd + 8];
        const int mrow = b*SEQ + qt*128 + wave*32 + g*16 + qr;
        *(uint4*)&xb[(size_t)mrow*CDIM + h*HD + dd]     = oa;
        *(uint4*)&xb[(size_t)mrow*CDIM + h*HD + dd + 8] = ob;
    }
}

extern "C" void kernel_launch(void* const* d_in, const int* in_sizes, int n_in,
                              void* d_out, int out_size, void* d_ws, size_t ws_size,
                              hipStream_t stream)
{
    const float* q  = (const float*)d_in[0];
    const float* k  = (const float*)d_in[1];
    const float* v  = (const float*)d_in[2];
    const float* Wq = (const float*)d_in[3];
    const float* Wp = (const float*)d_in[4];
    const float* bp = (const float*)d_in[5];
    float* out = (float*)d_out;

    char* p = (char*)d_ws;
    auto carve = [&](size_t bytes) { char* r = p; p += (bytes + 255) & ~(size_t)255; return r; };
    unsigned short* Abuf   = (unsigned short*)carve((size_t)MROWS*K3C*2);
    unsigned short* Wqkvb  = (unsigned short*)carve((size_t)K3C*K3C*2);
    unsigned short* Wprojb = (unsigned short*)carve((size_t)CDIM*CDIM*2);
    unsigned short* qhb    = (unsigned short*)carve((size_t)BATCH*HEADS*SEQ*HD*2);
    unsigned short* khb    = (unsigned short*)carve((size_t)BATCH*HEADS*SEQ*HD*2);
    unsigned short* vtb    = (unsigned short*)carve((size_t)BATCH*HEADS*SEQ*HD*2);
    unsigned short* xbuf   = (unsigned short*)carve((size_t)MROWS*CDIM*2);

    cast_all<<<MROWS + 9216 + 1024, 256, 0, stream>>>(q, k, v, Wq, Wp, Abuf, Wqkvb, Wprojb);

    gemm256_qkv<<<dim3(256), 512, 0, stream>>>(Abuf, Wqkvb, qhb, khb, vtb);

    attention<<<dim3(SEQ/128, HEADS, BATCH), 256, 0, stream>>>(qhb, khb, vtb, xbuf);

    gemm_bt<1><<<dim3(MROWS/128, CDIM/128), 256, 0, stream>>>(
        xbuf, Wprojb, MROWS, CDIM, CDIM, nullptr, nullptr, nullptr, bp, out);
}

// Round 5
// 284.756 us; speedup vs baseline: 1.0717x; 1.0099x over previous
//
#include <hip/hip_runtime.h>
#include <hip/hip_bf16.h>
#include <stdint.h>

#define HEADS 16
#define HD 64
#define SEQ 2048
#define BATCH 2
#define CDIM 1024
#define MROWS (BATCH*SEQ)   // 4096
#define K3C (3*CDIM)        // 3072
// Q prescale: attn scale 1/8 times log2(e), so softmax uses exp2 directly
#define QSCALE 0.1803368801111244f

typedef __bf16 bf16x8 __attribute__((ext_vector_type(8)));
typedef float  f32x4  __attribute__((ext_vector_type(4)));

__device__ __forceinline__ unsigned short f2bf(float f) {
    __hip_bfloat16 h = __float2bfloat16(f);
    return __builtin_bit_cast(unsigned short, h);
}
__device__ __forceinline__ unsigned int pack2bf(float a, float b) {
    return (unsigned int)f2bf(a) | ((unsigned int)f2bf(b) << 16);
}
__device__ __forceinline__ bf16x8 frag(uint4 u) { return __builtin_bit_cast(bf16x8, u); }

// async global->LDS: per-lane global gather -> contiguous LDS (base + lane*16)
__device__ __forceinline__ void async16(const unsigned short* g, unsigned short* lds) {
    __builtin_amdgcn_global_load_lds(
        (const __attribute__((address_space(1))) unsigned int*)g,
        (__attribute__((address_space(3))) unsigned int*)lds, 16, 0, 0);
}

// inline-asm ds_read_b128 hidden from the LDS-DMA hazard pass (keeps the
// counted-vmcnt pipeline); must be followed by a counted lgkmcnt +
// sched_barrier(0) before consuming MFMAs (rule #18).
__device__ __forceinline__ void dsr(uint4& d, unsigned addr, unsigned imm) {
    asm volatile("ds_read_b128 %0, %1 offset:%c2" : "=v"(d) : "v"(addr), "i"(imm));
}

// ---------------- fused cast kernel ----------------
__global__ void cast_all(const float* __restrict__ q, const float* __restrict__ k,
                         const float* __restrict__ v, const float* __restrict__ Wq,
                         const float* __restrict__ Wp,
                         unsigned short* __restrict__ A, unsigned short* __restrict__ Wqb,
                         unsigned short* __restrict__ Wpb)
{
    const int bid = blockIdx.x;
    const int t = threadIdx.x;
    if (bid < MROWS) {
        const float* srcs[3] = {q, k, v};
        #pragma unroll
        for (int i = 0; i < 3; ++i) {
            float4 f = *(const float4*)(srcs[i] + (size_t)bid*CDIM + t*4);
            ushort4 s;
            s.x = f2bf(f.x); s.y = f2bf(f.y); s.z = f2bf(f.z); s.w = f2bf(f.w);
            *(ushort4*)(A + (size_t)bid*K3C + i*CDIM + t*4) = s;
        }
    } else if (bid < MROWS + 9216) {
        int idx = (bid - MROWS)*256 + t;
        float4 f = ((const float4*)Wq)[idx];
        ushort4 s;
        s.x = f2bf(f.x); s.y = f2bf(f.y); s.z = f2bf(f.z); s.w = f2bf(f.w);
        ((ushort4*)Wqb)[idx] = s;
    } else {
        int idx = (bid - MROWS - 9216)*256 + t;
        float4 f = ((const float4*)Wp)[idx];
        ushort4 s;
        s.x = f2bf(f.x); s.y = f2bf(f.y); s.z = f2bf(f.z); s.w = f2bf(f.w);
        ((ushort4*)Wpb)[idx] = s;
    }
}

// ---------------- m97-style bf16 GEMM (BK=32) — kept for the proj GEMM ----------------
template<int EPI>
__global__ __launch_bounds__(256, 2)
void gemm_bt(const unsigned short* __restrict__ A, const unsigned short* __restrict__ B,
             int M, int N, int K,
             unsigned short* __restrict__ qh, unsigned short* __restrict__ kh,
             unsigned short* __restrict__ vt,
             const float* __restrict__ bias, float* __restrict__ out)
{
    __shared__ __attribute__((aligned(16))) unsigned short As[128*32];
    __shared__ __attribute__((aligned(16))) unsigned short Bs[128*32];
    const int tid  = threadIdx.x;
    const int wave = tid >> 6;
    const int lane = tid & 63;
    const int l15  = lane & 15;
    const int quad = lane >> 4;
    const int wm = (wave >> 1) * 64;
    const int wn = (wave & 1) * 64;
    const int m0 = blockIdx.x * 128;
    const int n0 = blockIdx.y * 128;

    f32x4 acc[4][4] = {};

    const int srow = tid >> 2;
    const int sc8  = (tid & 3) * 8;

    for (int k0 = 0; k0 < K; k0 += 32) {
        #pragma unroll
        for (int t = 0; t < 2; ++t) {
            int row = t*64 + srow;
            const unsigned short* ga = A + (size_t)(m0 + row)*K + k0 + sc8;
            const unsigned short* gb = B + (size_t)(n0 + row)*K + k0 + sc8;
            async16(ga, &As[(t*256 + wave*64)*8]);
            async16(gb, &Bs[(t*256 + wave*64)*8]);
        }
        __syncthreads();
        uint4 af[4], bfv[4];
        #pragma unroll
        for (int i = 0; i < 4; ++i) {
            af[i]  = *(const uint4*)&As[(wm + i*16 + l15)*32 + quad*8];
            bfv[i] = *(const uint4*)&Bs[(wn + i*16 + l15)*32 + quad*8];
        }
        #pragma unroll
        for (int mi = 0; mi < 4; ++mi)
            #pragma unroll
            for (int ni = 0; ni < 4; ++ni)
                acc[mi][ni] = __builtin_amdgcn_mfma_f32_16x16x32_bf16(
                    frag(af[mi]), frag(bfv[ni]), acc[mi][ni], 0, 0, 0);
        __syncthreads();
    }

    if constexpr (EPI == 0) {
        #pragma unroll
        for (int mi = 0; mi < 4; ++mi) {
            int row0 = m0 + wm + mi*16 + quad*4;
            int b  = row0 >> 11;
            int nq = row0 & 2047;
            #pragma unroll
            for (int ni = 0; ni < 4; ++ni) {
                int col   = n0 + wn + ni*16 + l15;
                int which = col >> 10;
                int h     = (col >> 6) & 15;
                int d     = col & 63;
                int bh    = b*HEADS + h;
                if (which == 2) {
                    ushort4 pv;
                    pv.x = f2bf(acc[mi][ni][0]);
                    pv.y = f2bf(acc[mi][ni][1]);
                    pv.z = f2bf(acc[mi][ni][2]);
                    pv.w = f2bf(acc[mi][ni][3]);
                    *(ushort4*)&vt[((size_t)bh*HD + d)*SEQ + nq] = pv;
                } else {
                    unsigned short* dst = (which == 0) ? qh : kh;
                    float sc = (which == 0) ? QSCALE : 1.0f;
                    #pragma unroll
                    for (int r = 0; r < 4; ++r)
                        dst[((size_t)bh*SEQ + nq + r)*HD + d] = f2bf(acc[mi][ni][r] * sc);
                }
            }
        }
    } else {
        #pragma unroll
        for (int mi = 0; mi < 4; ++mi) {
            int row0 = m0 + wm + mi*16 + quad*4;
            #pragma unroll
            for (int ni = 0; ni < 4; ++ni) {
                int col  = n0 + wn + ni*16 + l15;
                float bv = bias[col];
                #pragma unroll
                for (int r = 0; r < 4; ++r)
                    out[(size_t)(row0 + r)*N + col] = acc[mi][ni][r] + bv;
            }
        }
    }
}

// ---------------- 256x192 1-phase split-wait bf16 GEMM for the QKV projection ----------
// Round-5 delta vs round 4 (geometry/mapping/staging/epilogue identical, all
// harness-verified): merge to ONE phase per K-tile with SPLIT lgkm waits so the
// LDS pipe and the MFMA pipe overlap within each wave:
//   issue all 22 ds_reads, kc0-first (A kc0 x8, B kc0 x3 | A kc1 x8, B kc1 x3)
//   s_waitcnt lgkmcnt(11)  -> kc0 operands ready; kc1 reads still draining
//   24 MFMA (kc0)          -> overlaps the kc1 LDS drain
//   s_waitcnt lgkmcnt(0) ; s_barrier   <- WAR fence: ALL waves' reads complete
//   24 MFMA (kc1)
//   stage(t+2) + vmcnt(7)  -> counted prefetch, never drained in steady state
//   s_barrier              <- buf (t+1)&1 fully staged
// Barrier events/tile: 4 -> 2, and the stage-vs-read WAR race of round 4 is now
// closed by construction (stage is issued only after the mid barrier).
#define NT48 48

__global__ __launch_bounds__(512, 2)
void gemm256_qkv(const unsigned short* __restrict__ A, const unsigned short* __restrict__ B,
                 unsigned short* __restrict__ qh, unsigned short* __restrict__ kh,
                 unsigned short* __restrict__ vt)
{
    __shared__ __attribute__((aligned(16))) unsigned short As[2*16384]; // 2 x 32KB
    __shared__ __attribute__((aligned(16))) unsigned short Bs[2*12288]; // 2 x 24KB

    const int tid  = threadIdx.x;
    const int wave = tid >> 6;
    const int lane = tid & 63;
    const int l15  = lane & 15;
    const int quad = lane >> 4;
    const int wr   = wave >> 2;   // 0..1  (M: 128 rows each)
    const int wc   = wave & 3;    // 0..3  (N: 48 cols each)

    // XCD-aware bijective swizzle: 256 blocks, 256 % 8 == 0, 32 per XCD
    const int id  = blockIdx.x;
    const int swz = (id & 7)*32 + (id >> 3);
    const int m0  = (swz & 15) * 256;   // 16 M-tiles
    const int n0  = (swz >> 4) * 192;   // 16 N-tiles

    // ---- staging precompute: unit u, this thread's (global element offset, LDS dst)
    // byte P within region -> subtile st=P>>10 (rb=st>>1, kc=st&1); within subtile
    // apply involution ql = q ^ ((q>>9&1)<<5); row=ql>>6, kbyte=ql&63.
    size_t aSrc[4]; size_t bSrc[3];
    #pragma unroll
    for (int u = 0; u < 4; ++u) {
        int P  = u*8192 + tid*16;
        int st = P >> 10, q = P & 1023;
        int ql = q ^ (((q >> 9) & 1) << 5);
        int row = m0 + (st >> 1)*16 + (ql >> 6);
        int kel = (st & 1)*32 + ((ql & 63) >> 1);
        aSrc[u] = (size_t)row*K3C + kel;
    }
    #pragma unroll
    for (int u = 0; u < 3; ++u) {
        int P  = u*8192 + tid*16;
        int st = P >> 10, q = P & 1023;
        int ql = q ^ (((q >> 9) & 1) << 5);
        int row = n0 + (st >> 1)*16 + (ql >> 6);
        int kel = (st & 1)*32 + ((ql & 63) >> 1);
        bSrc[u] = (size_t)row*K3C + kel;
    }
    const int wdst = wave*512;  // shorts; per-unit dst = base + hb*region + u*4096 + wdst

    auto stage = [&](int t) {
        const int hb = t & 1;
        #pragma unroll
        for (int u = 0; u < 4; ++u)
            async16(A + aSrc[u] + t*64, As + hb*16384 + u*4096 + wdst);
        #pragma unroll
        for (int u = 0; u < 3; ++u)
            async16(B + bSrc[u] + t*64, Bs + hb*12288 + u*4096 + wdst);
    };

    // per-lane swizzled ds_read byte offset within a 1KB subtile
    const unsigned lanebyte = (unsigned)((l15*64 + quad*16) ^ ((l15 & 8) << 2));
    const unsigned aAddr = (unsigned)(uintptr_t)&As[0] + lanebyte + (unsigned)(wr*16384);
    const unsigned bAddr = (unsigned)(uintptr_t)&Bs[0] + lanebyte + (unsigned)(wc*6144);

    f32x4 acc[8][3] = {};

    // prologue: tiles 0 and 1 staged; wait tile0 (7 newest = tile1 in flight)
    stage(0); stage(1);
    asm volatile("s_waitcnt vmcnt(7)" ::: "memory");
    __builtin_amdgcn_s_barrier();

    for (int tt = 0; tt < NT48; tt += 2) {
        #pragma unroll
        for (int hb = 0; hb < 2; ++hb) {
            const int t = tt + hb;                       // t&1 == hb
            uint4 a0[8], b0[3], a1[8], b1[3];

            // issue all reads, kc0 cluster first (11), then kc1 cluster (11)
            #pragma unroll
            for (int mi = 0; mi < 8; ++mi)
                dsr(a0[mi], aAddr, hb*32768 + mi*2048);
            #pragma unroll
            for (int ni = 0; ni < 3; ++ni)
                dsr(b0[ni], bAddr, hb*24576 + ni*2048);
            #pragma unroll
            for (int mi = 0; mi < 8; ++mi)
                dsr(a1[mi], aAddr, hb*32768 + mi*2048 + 1024);
            #pragma unroll
            for (int ni = 0; ni < 3; ++ni)
                dsr(b1[ni], bAddr, hb*24576 + ni*2048 + 1024);

            // kc0 operands ready; kc1 reads still in flight behind the MFMAs
            asm volatile("s_waitcnt lgkmcnt(11)" ::: "memory");
            __builtin_amdgcn_sched_barrier(0);
            __builtin_amdgcn_s_setprio(1);
            #pragma unroll
            for (int mi = 0; mi < 8; ++mi)
                #pragma unroll
                for (int ni = 0; ni < 3; ++ni)
                    acc[mi][ni] = __builtin_amdgcn_mfma_f32_16x16x32_bf16(
                        frag(a0[mi]), frag(b0[ni]), acc[mi][ni], 0, 0, 0);
            __builtin_amdgcn_s_setprio(0);

            // all of this wave's reads done; barrier => ALL waves' reads done
            asm volatile("s_waitcnt lgkmcnt(0)" ::: "memory");
            __builtin_amdgcn_sched_barrier(0);
            __builtin_amdgcn_s_barrier();

            __builtin_amdgcn_s_setprio(1);
            #pragma unroll
            for (int mi = 0; mi < 8; ++mi)
                #pragma unroll
                for (int ni = 0; ni < 3; ++ni)
                    acc[mi][ni] = __builtin_amdgcn_mfma_f32_16x16x32_bf16(
                        frag(a1[mi]), frag(b1[ni]), acc[mi][ni], 0, 0, 0);
            __builtin_amdgcn_s_setprio(0);

            // counted prefetch: buf hb is safe to overwrite (mid barrier passed)
            if (t + 2 < NT48)      { stage(t + 2);
                                     asm volatile("s_waitcnt vmcnt(7)" ::: "memory"); }
            else if (t + 1 < NT48) { asm volatile("s_waitcnt vmcnt(0)" ::: "memory"); }
            __builtin_amdgcn_s_barrier();
        }
    }

    // epilogue: route into qh (scaled), kh, vt (transposed); per-column decode
    #pragma unroll
    for (int mi = 0; mi < 8; ++mi) {
        const int row0 = m0 + wr*128 + mi*16 + quad*4;
        const int b  = row0 >> 11;
        const int nq = row0 & 2047;
        #pragma unroll
        for (int ni = 0; ni < 3; ++ni) {
            const int col   = n0 + wc*48 + ni*16 + l15;
            const int which = col >> 10;
            const int h     = (col >> 6) & 15;
            const int d     = col & 63;
            const int bh_   = b*HEADS + h;
            if (which == 2) {
                ushort4 pv;
                pv.x = f2bf(acc[mi][ni][0]);
                pv.y = f2bf(acc[mi][ni][1]);
                pv.z = f2bf(acc[mi][ni][2]);
                pv.w = f2bf(acc[mi][ni][3]);
                *(ushort4*)&vt[((size_t)bh_*HD + d)*SEQ + nq] = pv;
            } else {
                unsigned short* dst = (which == 0) ? qh : kh;
                float sc = (which == 0) ? QSCALE : 1.0f;
                #pragma unroll
                for (int r = 0; r < 4; ++r)
                    dst[((size_t)bh_*SEQ + nq + r)*HD + d] = f2bf(acc[mi][ni][r] * sc);
            }
        }
    }
}

// ---------------- flash attention: 32 q/wave + async double-buffered K/V ----------------
__global__ __launch_bounds__(256, 2)
void attention(const unsigned short* __restrict__ qh, const unsigned short* __restrict__ kh,
               const unsigned short* __restrict__ vt, unsigned short* __restrict__ xb)
{
    const int qt = blockIdx.x;          // 0..15 (tiles of 128 q)
    const int h  = blockIdx.y;
    const int b  = blockIdx.z;
    const int bh = b*HEADS + h;
    const int tid  = threadIdx.x;
    const int wave = tid >> 6;
    const int lane = tid & 63;
    const int l15  = lane & 15;
    const int quad = lane >> 4;

    __shared__ __attribute__((aligned(16))) unsigned short Ks[2][64*64];
    __shared__ __attribute__((aligned(16))) unsigned short Vs[2][64*64];
    __shared__ __attribute__((aligned(16))) unsigned short Ps[4][2*16*72];

    const unsigned short* Qp = qh + ((size_t)bh*SEQ + qt*128 + wave*32)*HD;
    const unsigned short* Kp = kh + (size_t)bh*SEQ*HD;
    const unsigned short* Vp = vt + (size_t)bh*HD*SEQ;

    auto stage = [&](int kt, int bufI) {
        #pragma unroll
        for (int t = 0; t < 2; ++t) {
            int c  = t*256 + wave*64 + lane;   // chunk index 0..511
            int r  = c >> 3;
            int cc = (c & 7) ^ (r & 7);
            async16(Kp + (size_t)(kt*64 + r)*HD + cc*8,
                    &Ks[bufI][(t*256 + wave*64)*8]);
            async16(Vp + (size_t)r*SEQ + kt*64 + cc*8,
                    &Vs[bufI][(t*256 + wave*64)*8]);
        }
    };

    stage(0, 0);

    uint4 qf[2][2];
    #pragma unroll
    for (int g = 0; g < 2; ++g) {
        qf[g][0] = *(const uint4*)(Qp + (size_t)(g*16 + l15)*HD + quad*8);
        qf[g][1] = *(const uint4*)(Qp + (size_t)(g*16 + l15)*HD + 32 + quad*8);
    }

    f32x4 o[2][4] = {};
    float m_s[2] = {-INFINITY, -INFINITY};
    float l_s[2] = {0.f, 0.f};

    unsigned short* Pw = Ps[wave];
    const int x7 = l15 & 7;

    for (int kt = 0; kt < SEQ/64; ++kt) {
        stage((kt + 1) & 31, (kt + 1) & 1);
        asm volatile("s_waitcnt vmcnt(4)" ::: "memory");
        asm volatile("s_barrier" ::: "memory");

        const unsigned short* Kb = Ks[kt & 1];
        const unsigned short* Vb = Vs[kt & 1];

        f32x4 s[2][4];
        #pragma unroll
        for (int st = 0; st < 4; ++st) {
            int rb = st*16 + l15;
            uint4 kf0 = *(const uint4*)&Kb[(rb*8 + (quad ^ x7))*8];
            uint4 kf1 = *(const uint4*)&Kb[(rb*8 + ((4 + quad) ^ x7))*8];
            #pragma unroll
            for (int g = 0; g < 2; ++g) {
                f32x4 z = {};
                z = __builtin_amdgcn_mfma_f32_16x16x32_bf16(frag(kf0), frag(qf[g][0]), z, 0, 0, 0);
                z = __builtin_amdgcn_mfma_f32_16x16x32_bf16(frag(kf1), frag(qf[g][1]), z, 0, 0, 0);
                s[g][st] = z;
            }
        }

        #pragma unroll
        for (int g = 0; g < 2; ++g) {
            float mloc = s[g][0][0];
            #pragma unroll
            for (int st = 0; st < 4; ++st)
                #pragma unroll
                for (int r = 0; r < 4; ++r)
                    mloc = fmaxf(mloc, s[g][st][r]);
            mloc = fmaxf(mloc, __shfl_xor(mloc, 16));
            mloc = fmaxf(mloc, __shfl_xor(mloc, 32));

            float mn = fmaxf(m_s[g], mloc);
            float al = __builtin_amdgcn_exp2f(m_s[g] - mn);
            m_s[g] = mn;

            float rs = 0.f;
            float p[4][4];
            #pragma unroll
            for (int st = 0; st < 4; ++st)
                #pragma unroll
                for (int r = 0; r < 4; ++r) {
                    p[st][r] = __builtin_amdgcn_exp2f(s[g][st][r] - mn);
                    rs += p[st][r];
                }
            rs += __shfl_xor(rs, 16);
            rs += __shfl_xor(rs, 32);
            l_s[g] = al*l_s[g] + rs;

            #pragma unroll
            for (int st = 0; st < 4; ++st)
                #pragma unroll
                for (int r = 0; r < 4; ++r)
                    o[g][st][r] *= al;

            #pragma unroll
            for (int st = 0; st < 4; ++st) {
                uint2 pk;
                pk.x = pack2bf(p[st][0], p[st][1]);
                pk.y = pack2bf(p[st][2], p[st][3]);
                *(uint2*)&Pw[g*1152 + l15*72 + st*16 + quad*4] = pk;
            }
        }
        asm volatile("s_waitcnt lgkmcnt(0)" ::: "memory");

        uint4 pB[2][2];
        #pragma unroll
        for (int g = 0; g < 2; ++g) {
            pB[g][0] = *(const uint4*)&Pw[g*1152 + l15*72 + quad*8];
            pB[g][1] = *(const uint4*)&Pw[g*1152 + l15*72 + 32 + quad*8];
        }

        #pragma unroll
        for (int st = 0; st < 4; ++st) {
            int rb = st*16 + l15;
            uint4 vf0 = *(const uint4*)&Vb[(rb*8 + (quad ^ x7))*8];
            uint4 vf1 = *(const uint4*)&Vb[(rb*8 + ((4 + quad) ^ x7))*8];
            #pragma unroll
            for (int g = 0; g < 2; ++g) {
                o[g][st] = __builtin_amdgcn_mfma_f32_16x16x32_bf16(frag(vf0), frag(pB[g][0]), o[g][st], 0, 0, 0);
                o[g][st] = __builtin_amdgcn_mfma_f32_16x16x32_bf16(frag(vf1), frag(pB[g][1]), o[g][st], 0, 0, 0);
            }
        }

        asm volatile("s_barrier" ::: "memory");
    }

    #pragma unroll
    for (int g = 0; g < 2; ++g) {
        float inv = 1.0f / l_s[g];
        #pragma unroll
        for (int st = 0; st < 4; ++st) {
            uint2 pk;
            pk.x = pack2bf(o[g][st][0]*inv, o[g][st][1]*inv);
            pk.y = pack2bf(o[g][st][2]*inv, o[g][st][3]*inv);
            *(uint2*)&Pw[g*1152 + l15*72 + st*16 + quad*4] = pk;
        }
    }
    asm volatile("s_waitcnt lgkmcnt(0)" ::: "memory");

    const int qr = lane >> 2;          // 0..15
    const int dd = (lane & 3) * 16;    // 0,16,32,48
    #pragma unroll
    for (int g = 0; g < 2; ++g) {
        uint4 oa = *(const uint4*)&Pw[g*1152 + qr*72 + dd];
        uint4 ob = *(const uint4*)&Pw[g*1152 + qr*72 + dd + 8];
        const int mrow = b*SEQ + qt*128 + wave*32 + g*16 + qr;
        *(uint4*)&xb[(size_t)mrow*CDIM + h*HD + dd]     = oa;
        *(uint4*)&xb[(size_t)mrow*CDIM + h*HD + dd + 8] = ob;
    }
}

extern "C" void kernel_launch(void* const* d_in, const int* in_sizes, int n_in,
                              void* d_out, int out_size, void* d_ws, size_t ws_size,
                              hipStream_t stream)
{
    const float* q  = (const float*)d_in[0];
    const float* k  = (const float*)d_in[1];
    const float* v  = (const float*)d_in[2];
    const float* Wq = (const float*)d_in[3];
    const float* Wp = (const float*)d_in[4];
    const float* bp = (const float*)d_in[5];
    float* out = (float*)d_out;

    char* p = (char*)d_ws;
    auto carve = [&](size_t bytes) { char* r = p; p += (bytes + 255) & ~(size_t)255; return r; };
    unsigned short* Abuf   = (unsigned short*)carve((size_t)MROWS*K3C*2);
    unsigned short* Wqkvb  = (unsigned short*)carve((size_t)K3C*K3C*2);
    unsigned short* Wprojb = (unsigned short*)carve((size_t)CDIM*CDIM*2);
    unsigned short* qhb    = (unsigned short*)carve((size_t)BATCH*HEADS*SEQ*HD*2);
    unsigned short* khb    = (unsigned short*)carve((size_t)BATCH*HEADS*SEQ*HD*2);
    unsigned short* vtb    = (unsigned short*)carve((size_t)BATCH*HEADS*SEQ*HD*2);
    unsigned short* xbuf   = (unsigned short*)carve((size_t)MROWS*CDIM*2);

    cast_all<<<MROWS + 9216 + 1024, 256, 0, stream>>>(q, k, v, Wq, Wp, Abuf, Wqkvb, Wprojb);

    gemm256_qkv<<<dim3(256), 512, 0, stream>>>(Abuf, Wqkvb, qhb, khb, vtb);

    attention<<<dim3(SEQ/128, HEADS, BATCH), 256, 0, stream>>>(qhb, khb, vtb, xbuf);

    gemm_bt<1><<<dim3(MROWS/128, CDIM/128), 256, 0, stream>>>(
        xbuf, Wprojb, MROWS, CDIM, CDIM, nullptr, nullptr, nullptr, bp, out);
}

// Round 7
// 272.327 us; speedup vs baseline: 1.1206x; 1.0456x over previous
//
#include <hip/hip_runtime.h>
#include <hip/hip_bf16.h>
#include <stdint.h>

#define HEADS 16
#define HD 64
#define SEQ 2048
#define BATCH 2
#define CDIM 1024
#define MROWS (BATCH*SEQ)   // 4096
#define K3C (3*CDIM)        // 3072
// Q prescale: attn scale 1/8 times log2(e), so softmax uses exp2 directly
#define QSCALE 0.1803368801111244f

typedef __bf16 bf16x8 __attribute__((ext_vector_type(8)));
typedef float  f32x4  __attribute__((ext_vector_type(4)));

__device__ __forceinline__ unsigned short f2bf(float f) {
    __hip_bfloat16 h = __float2bfloat16(f);
    return __builtin_bit_cast(unsigned short, h);
}
__device__ __forceinline__ unsigned int pack2bf(float a, float b) {
    return (unsigned int)f2bf(a) | ((unsigned int)f2bf(b) << 16);
}
__device__ __forceinline__ bf16x8 frag(uint4 u) { return __builtin_bit_cast(bf16x8, u); }

// async global->LDS: per-lane global gather -> contiguous LDS (base + lane*16)
__device__ __forceinline__ void async16(const unsigned short* g, unsigned short* lds) {
    __builtin_amdgcn_global_load_lds(
        (const __attribute__((address_space(1))) unsigned int*)g,
        (__attribute__((address_space(3))) unsigned int*)lds, 16, 0, 0);
}

// inline-asm ds_read_b128 hidden from the LDS-DMA hazard pass (keeps the
// counted-vmcnt pipeline); must be followed by a counted lgkmcnt +
// sched_barrier(0) before consuming MFMAs (rule #18).
__device__ __forceinline__ void dsr(uint4& d, unsigned addr, unsigned imm) {
    asm volatile("ds_read_b128 %0, %1 offset:%c2" : "=v"(d) : "v"(addr), "i"(imm));
}

// ---------------- fused cast kernel ----------------
__global__ void cast_all(const float* __restrict__ q, const float* __restrict__ k,
                         const float* __restrict__ v, const float* __restrict__ Wq,
                         const float* __restrict__ Wp,
                         unsigned short* __restrict__ A, unsigned short* __restrict__ Wqb,
                         unsigned short* __restrict__ Wpb)
{
    const int bid = blockIdx.x;
    const int t = threadIdx.x;
    if (bid < MROWS) {
        const float* srcs[3] = {q, k, v};
        #pragma unroll
        for (int i = 0; i < 3; ++i) {
            float4 f = *(const float4*)(srcs[i] + (size_t)bid*CDIM + t*4);
            ushort4 s;
            s.x = f2bf(f.x); s.y = f2bf(f.y); s.z = f2bf(f.z); s.w = f2bf(f.w);
            *(ushort4*)(A + (size_t)bid*K3C + i*CDIM + t*4) = s;
        }
    } else if (bid < MROWS + 9216) {
        int idx = (bid - MROWS)*256 + t;
        float4 f = ((const float4*)Wq)[idx];
        ushort4 s;
        s.x = f2bf(f.x); s.y = f2bf(f.y); s.z = f2bf(f.z); s.w = f2bf(f.w);
        ((ushort4*)Wqb)[idx] = s;
    } else {
        int idx = (bid - MROWS - 9216)*256 + t;
        float4 f = ((const float4*)Wp)[idx];
        ushort4 s;
        s.x = f2bf(f.x); s.y = f2bf(f.y); s.z = f2bf(f.z); s.w = f2bf(f.w);
        ((ushort4*)Wpb)[idx] = s;
    }
}

// ---------------- m97-style bf16 GEMM (BK=32) — kept for the proj GEMM ----------------
template<int EPI>
__global__ __launch_bounds__(256, 2)
void gemm_bt(const unsigned short* __restrict__ A, const unsigned short* __restrict__ B,
             int M, int N, int K,
             unsigned short* __restrict__ qh, unsigned short* __restrict__ kh,
             unsigned short* __restrict__ vt,
             const float* __restrict__ bias, float* __restrict__ out)
{
    __shared__ __attribute__((aligned(16))) unsigned short As[128*32];
    __shared__ __attribute__((aligned(16))) unsigned short Bs[128*32];
    const int tid  = threadIdx.x;
    const int wave = tid >> 6;
    const int lane = tid & 63;
    const int l15  = lane & 15;
    const int quad = lane >> 4;
    const int wm = (wave >> 1) * 64;
    const int wn = (wave & 1) * 64;
    const int m0 = blockIdx.x * 128;
    const int n0 = blockIdx.y * 128;

    f32x4 acc[4][4] = {};

    const int srow = tid >> 2;
    const int sc8  = (tid & 3) * 8;

    for (int k0 = 0; k0 < K; k0 += 32) {
        #pragma unroll
        for (int t = 0; t < 2; ++t) {
            int row = t*64 + srow;
            const unsigned short* ga = A + (size_t)(m0 + row)*K + k0 + sc8;
            const unsigned short* gb = B + (size_t)(n0 + row)*K + k0 + sc8;
            async16(ga, &As[(t*256 + wave*64)*8]);
            async16(gb, &Bs[(t*256 + wave*64)*8]);
        }
        __syncthreads();
        uint4 af[4], bfv[4];
        #pragma unroll
        for (int i = 0; i < 4; ++i) {
            af[i]  = *(const uint4*)&As[(wm + i*16 + l15)*32 + quad*8];
            bfv[i] = *(const uint4*)&Bs[(wn + i*16 + l15)*32 + quad*8];
        }
        #pragma unroll
        for (int mi = 0; mi < 4; ++mi)
            #pragma unroll
            for (int ni = 0; ni < 4; ++ni)
                acc[mi][ni] = __builtin_amdgcn_mfma_f32_16x16x32_bf16(
                    frag(af[mi]), frag(bfv[ni]), acc[mi][ni], 0, 0, 0);
        __syncthreads();
    }

    if constexpr (EPI == 0) {
        #pragma unroll
        for (int mi = 0; mi < 4; ++mi) {
            int row0 = m0 + wm + mi*16 + quad*4;
            int b  = row0 >> 11;
            int nq = row0 & 2047;
            #pragma unroll
            for (int ni = 0; ni < 4; ++ni) {
                int col   = n0 + wn + ni*16 + l15;
                int which = col >> 10;
                int h     = (col >> 6) & 15;
                int d     = col & 63;
                int bh    = b*HEADS + h;
                if (which == 2) {
                    ushort4 pv;
                    pv.x = f2bf(acc[mi][ni][0]);
                    pv.y = f2bf(acc[mi][ni][1]);
                    pv.z = f2bf(acc[mi][ni][2]);
                    pv.w = f2bf(acc[mi][ni][3]);
                    *(ushort4*)&vt[((size_t)bh*HD + d)*SEQ + nq] = pv;
                } else {
                    unsigned short* dst = (which == 0) ? qh : kh;
                    float sc = (which == 0) ? QSCALE : 1.0f;
                    #pragma unroll
                    for (int r = 0; r < 4; ++r)
                        dst[((size_t)bh*SEQ + nq + r)*HD + d] = f2bf(acc[mi][ni][r] * sc);
                }
            }
        }
    } else {
        #pragma unroll
        for (int mi = 0; mi < 4; ++mi) {
            int row0 = m0 + wm + mi*16 + quad*4;
            #pragma unroll
            for (int ni = 0; ni < 4; ++ni) {
                int col  = n0 + wn + ni*16 + l15;
                float bv = bias[col];
                #pragma unroll
                for (int r = 0; r < 4; ++r)
                    out[(size_t)(row0 + r)*N + col] = acc[mi][ni][r] + bv;
            }
        }
    }
}

// ---------------- 256x192 1-phase split-wait bf16 GEMM for the QKV projection ----------
// vt epilogue key index permuted (pi^-1 within each 64-key tile) so the attention
// PV B-fragment is lane-resident with ZERO cross-lane movement (see attention).
// K-loop identical to round 5 (harness-verified).
// pi(hi*32+c*8+h*4+r) = hi*32 + h*16 + c*4 + r; store key L = st*16+qq*4+r
// at pos (st>>1)*32 + qq*8 + (st&1)*4 + r.
#define NT48 48

__global__ __launch_bounds__(512, 2)
void gemm256_qkv(const unsigned short* __restrict__ A, const unsigned short* __restrict__ B,
                 unsigned short* __restrict__ qh, unsigned short* __restrict__ kh,
                 unsigned short* __restrict__ vt)
{
    __shared__ __attribute__((aligned(16))) unsigned short As[2*16384]; // 2 x 32KB
    __shared__ __attribute__((aligned(16))) unsigned short Bs[2*12288]; // 2 x 24KB

    const int tid  = threadIdx.x;
    const int wave = tid >> 6;
    const int lane = tid & 63;
    const int l15  = lane & 15;
    const int quad = lane >> 4;
    const int wr   = wave >> 2;   // 0..1  (M: 128 rows each)
    const int wc   = wave & 3;    // 0..3  (N: 48 cols each)

    // XCD-aware bijective swizzle: 256 blocks, 256 % 8 == 0, 32 per XCD
    const int id  = blockIdx.x;
    const int swz = (id & 7)*32 + (id >> 3);
    const int m0  = (swz & 15) * 256;   // 16 M-tiles
    const int n0  = (swz >> 4) * 192;   // 16 N-tiles

    size_t aSrc[4]; size_t bSrc[3];
    #pragma unroll
    for (int u = 0; u < 4; ++u) {
        int P  = u*8192 + tid*16;
        int st = P >> 10, q = P & 1023;
        int ql = q ^ (((q >> 9) & 1) << 5);
        int row = m0 + (st >> 1)*16 + (ql >> 6);
        int kel = (st & 1)*32 + ((ql & 63) >> 1);
        aSrc[u] = (size_t)row*K3C + kel;
    }
    #pragma unroll
    for (int u = 0; u < 3; ++u) {
        int P  = u*8192 + tid*16;
        int st = P >> 10, q = P & 1023;
        int ql = q ^ (((q >> 9) & 1) << 5);
        int row = n0 + (st >> 1)*16 + (ql >> 6);
        int kel = (st & 1)*32 + ((ql & 63) >> 1);
        bSrc[u] = (size_t)row*K3C + kel;
    }
    const int wdst = wave*512;

    auto stage = [&](int t) {
        const int hb = t & 1;
        #pragma unroll
        for (int u = 0; u < 4; ++u)
            async16(A + aSrc[u] + t*64, As + hb*16384 + u*4096 + wdst);
        #pragma unroll
        for (int u = 0; u < 3; ++u)
            async16(B + bSrc[u] + t*64, Bs + hb*12288 + u*4096 + wdst);
    };

    const unsigned lanebyte = (unsigned)((l15*64 + quad*16) ^ ((l15 & 8) << 2));
    const unsigned aAddr = (unsigned)(uintptr_t)&As[0] + lanebyte + (unsigned)(wr*16384);
    const unsigned bAddr = (unsigned)(uintptr_t)&Bs[0] + lanebyte + (unsigned)(wc*6144);

    f32x4 acc[8][3] = {};

    stage(0); stage(1);
    asm volatile("s_waitcnt vmcnt(7)" ::: "memory");
    __builtin_amdgcn_s_barrier();

    for (int tt = 0; tt < NT48; tt += 2) {
        #pragma unroll
        for (int hb = 0; hb < 2; ++hb) {
            const int t = tt + hb;                       // t&1 == hb
            uint4 a0[8], b0[3], a1[8], b1[3];

            #pragma unroll
            for (int mi = 0; mi < 8; ++mi)
                dsr(a0[mi], aAddr, hb*32768 + mi*2048);
            #pragma unroll
            for (int ni = 0; ni < 3; ++ni)
                dsr(b0[ni], bAddr, hb*24576 + ni*2048);
            #pragma unroll
            for (int mi = 0; mi < 8; ++mi)
                dsr(a1[mi], aAddr, hb*32768 + mi*2048 + 1024);
            #pragma unroll
            for (int ni = 0; ni < 3; ++ni)
                dsr(b1[ni], bAddr, hb*24576 + ni*2048 + 1024);

            asm volatile("s_waitcnt lgkmcnt(11)" ::: "memory");
            __builtin_amdgcn_sched_barrier(0);
            __builtin_amdgcn_s_setprio(1);
            #pragma unroll
            for (int mi = 0; mi < 8; ++mi)
                #pragma unroll
                for (int ni = 0; ni < 3; ++ni)
                    acc[mi][ni] = __builtin_amdgcn_mfma_f32_16x16x32_bf16(
                        frag(a0[mi]), frag(b0[ni]), acc[mi][ni], 0, 0, 0);
            __builtin_amdgcn_s_setprio(0);

            asm volatile("s_waitcnt lgkmcnt(0)" ::: "memory");
            __builtin_amdgcn_sched_barrier(0);
            __builtin_amdgcn_s_barrier();

            __builtin_amdgcn_s_setprio(1);
            #pragma unroll
            for (int mi = 0; mi < 8; ++mi)
                #pragma unroll
                for (int ni = 0; ni < 3; ++ni)
                    acc[mi][ni] = __builtin_amdgcn_mfma_f32_16x16x32_bf16(
                        frag(a1[mi]), frag(b1[ni]), acc[mi][ni], 0, 0, 0);
            __builtin_amdgcn_s_setprio(0);

            if (t + 2 < NT48)      { stage(t + 2);
                                     asm volatile("s_waitcnt vmcnt(7)" ::: "memory"); }
            else if (t + 1 < NT48) { asm volatile("s_waitcnt vmcnt(0)" ::: "memory"); }
            __builtin_amdgcn_s_barrier();
        }
    }

    // epilogue: qh (scaled), kh, vt (transposed + PV-slot permuted keys)
    #pragma unroll
    for (int mi = 0; mi < 8; ++mi) {
        const int row0 = m0 + wr*128 + mi*16 + quad*4;
        const int b  = row0 >> 11;
        const int nq = row0 & 2047;
        #pragma unroll
        for (int ni = 0; ni < 3; ++ni) {
            const int col   = n0 + wc*48 + ni*16 + l15;
            const int which = col >> 10;
            const int h     = (col >> 6) & 15;
            const int d     = col & 63;
            const int bh_   = b*HEADS + h;
            if (which == 2) {
                ushort4 pv;
                pv.x = f2bf(acc[mi][ni][0]);
                pv.y = f2bf(acc[mi][ni][1]);
                pv.z = f2bf(acc[mi][ni][2]);
                pv.w = f2bf(acc[mi][ni][3]);
                // pi^-1: key L = st*16 + quad*4 + r  ->  (quad + 4*(st>>1))*8 + (st&1)*4 + r
                const int st_ = mi & 3;
                const int nq2 = (nq & ~63) | ((quad + ((st_ >> 1) << 2)) << 3) | ((st_ & 1) << 2);
                *(ushort4*)&vt[((size_t)bh_*HD + d)*SEQ + nq2] = pv;
            } else {
                unsigned short* dst = (which == 0) ? qh : kh;
                float sc = (which == 0) ? QSCALE : 1.0f;
                #pragma unroll
                for (int r = 0; r < 4; ++r)
                    dst[((size_t)bh_*SEQ + nq + r)*HD + d] = f2bf(acc[mi][ni][r] * sc);
            }
        }
    }
}

// ---------------- flash attention: in-register P (zero-shuffle PV) ----------------
// (1) vt keys are pre-permuted (QKV epilogue) so the PV B-fragment = the lane's
// OWN packed P registers; P-LDS write + lgkmcnt(0) drain + read-back eliminated.
// (2) K/V frag reads via inline-asm ds_read_b128 (hidden from the LDS-DMA
// hazard pass -> vmcnt(4) prefetch survives), V issued early and drained behind
// QK^T via counted lgkmcnt(8).  (3) defer-max THR=8 (T13): skip the O-rescale
// pass when the tile max didn't grow past m_old+8 (wave-uniform via __all).
__global__ __launch_bounds__(256, 2)
void attention(const unsigned short* __restrict__ qh, const unsigned short* __restrict__ kh,
               const unsigned short* __restrict__ vt, unsigned short* __restrict__ xb)
{
    const int qt = blockIdx.x;          // 0..15 (tiles of 128 q)
    const int h  = blockIdx.y;
    const int b  = blockIdx.z;
    const int bh = b*HEADS + h;
    const int tid  = threadIdx.x;
    const int wave = tid >> 6;
    const int lane = tid & 63;
    const int l15  = lane & 15;
    const int quad = lane >> 4;

    __shared__ __attribute__((aligned(16))) unsigned short Ks[2][64*64];
    __shared__ __attribute__((aligned(16))) unsigned short Vs[2][64*64];
    __shared__ __attribute__((aligned(16))) unsigned short Ps[4][2*16*72];

    const unsigned short* Qp = qh + ((size_t)bh*SEQ + qt*128 + wave*32)*HD;
    const unsigned short* Kp = kh + (size_t)bh*SEQ*HD;
    const unsigned short* Vp = vt + (size_t)bh*HD*SEQ;

    auto stage = [&](int kt, int bufI) {
        #pragma unroll
        for (int t = 0; t < 2; ++t) {
            int c  = t*256 + wave*64 + lane;   // chunk index 0..511
            int r  = c >> 3;
            int cc = (c & 7) ^ (r & 7);
            async16(Kp + (size_t)(kt*64 + r)*HD + cc*8,
                    &Ks[bufI][(t*256 + wave*64)*8]);
            async16(Vp + (size_t)r*SEQ + kt*64 + cc*8,
                    &Vs[bufI][(t*256 + wave*64)*8]);
        }
    };

    stage(0, 0);

    uint4 qf[2][2];
    #pragma unroll
    for (int g = 0; g < 2; ++g) {
        qf[g][0] = *(const uint4*)(Qp + (size_t)(g*16 + l15)*HD + quad*8);
        qf[g][1] = *(const uint4*)(Qp + (size_t)(g*16 + l15)*HD + 32 + quad*8);
    }

    f32x4 o[2][4] = {};
    float m_s[2] = {-INFINITY, -INFINITY};
    float l_s[2] = {0.f, 0.f};

    const int x7 = l15 & 7;
    // per-lane LDS byte bases for the chunk-swizzled K/V tiles
    const unsigned ksBase = (unsigned)(uintptr_t)&Ks[0][0];
    const unsigned vsBase = (unsigned)(uintptr_t)&Vs[0][0];
    const unsigned laneA  = (unsigned)(l15*128 + (quad ^ x7)*16);        // chunk quad
    const unsigned laneB  = (unsigned)(l15*128 + ((quad ^ x7) ^ 4)*16);  // chunk 4+quad

    for (int kt = 0; kt < SEQ/64; ++kt) {
        stage((kt + 1) & 31, (kt + 1) & 1);
        asm volatile("s_waitcnt vmcnt(4)" ::: "memory");  // tile kt (and Q) landed
        asm volatile("s_barrier" ::: "memory");

        const unsigned bufo = (unsigned)((kt & 1) * 8192);
        const unsigned ka = ksBase + bufo + laneA, kb = ksBase + bufo + laneB;
        const unsigned va = vsBase + bufo + laneA, vb = vsBase + bufo + laneB;

        uint4 kf[4][2], vf[4][2];
        #pragma unroll
        for (int st = 0; st < 4; ++st) { dsr(kf[st][0], ka, st*2048); dsr(kf[st][1], kb, st*2048); }
        #pragma unroll
        for (int st = 0; st < 4; ++st) { dsr(vf[st][0], va, st*2048); dsr(vf[st][1], vb, st*2048); }

        asm volatile("s_waitcnt lgkmcnt(8)" ::: "memory");   // K ready; V drains behind QK^T
        __builtin_amdgcn_sched_barrier(0);

        f32x4 s[2][4];
        #pragma unroll
        for (int st = 0; st < 4; ++st)
            #pragma unroll
            for (int g = 0; g < 2; ++g) {
                f32x4 z = {};
                z = __builtin_amdgcn_mfma_f32_16x16x32_bf16(frag(kf[st][0]), frag(qf[g][0]), z, 0, 0, 0);
                z = __builtin_amdgcn_mfma_f32_16x16x32_bf16(frag(kf[st][1]), frag(qf[g][1]), z, 0, 0, 0);
                s[g][st] = z;
            }

        unsigned W[2][8];
        #pragma unroll
        for (int g = 0; g < 2; ++g) {
            float mloc = s[g][0][0];
            #pragma unroll
            for (int st = 0; st < 4; ++st)
                #pragma unroll
                for (int r = 0; r < 4; ++r)
                    mloc = fmaxf(mloc, s[g][st][r]);
            mloc = fmaxf(mloc, __shfl_xor(mloc, 16));
            mloc = fmaxf(mloc, __shfl_xor(mloc, 32));

            // defer-max: keep stale m while growth <= 8 (P bounded by 2^8)
            if (!__all(mloc - m_s[g] <= 8.0f)) {
                float mn = fmaxf(m_s[g], mloc);
                float al = __builtin_amdgcn_exp2f(m_s[g] - mn);
                m_s[g] = mn;
                l_s[g] *= al;
                #pragma unroll
                for (int st = 0; st < 4; ++st)
                    #pragma unroll
                    for (int r = 0; r < 4; ++r)
                        o[g][st][r] *= al;
            }
            const float mn = m_s[g];

            float rs = 0.f;
            float p[4][4];
            #pragma unroll
            for (int st = 0; st < 4; ++st)
                #pragma unroll
                for (int r = 0; r < 4; ++r) {
                    p[st][r] = __builtin_amdgcn_exp2f(s[g][st][r] - mn);
                    rs += p[st][r];
                }
            rs += __shfl_xor(rs, 16);
            rs += __shfl_xor(rs, 32);
            l_s[g] += rs;

            #pragma unroll
            for (int st = 0; st < 4; ++st) {
                W[g][st*2 + 0] = pack2bf(p[st][0], p[st][1]);
                W[g][st*2 + 1] = pack2bf(p[st][2], p[st][3]);
            }
        }

        asm volatile("s_waitcnt lgkmcnt(0)" ::: "memory");   // V frags ready
        __builtin_amdgcn_sched_barrier(0);

        #pragma unroll
        for (int g = 0; g < 2; ++g) {
            uint4 pb0, pb1;
            pb0.x = W[g][0]; pb0.y = W[g][1]; pb0.z = W[g][2]; pb0.w = W[g][3];
            pb1.x = W[g][4]; pb1.y = W[g][5]; pb1.z = W[g][6]; pb1.w = W[g][7];
            #pragma unroll
            for (int st = 0; st < 4; ++st) {
                o[g][st] = __builtin_amdgcn_mfma_f32_16x16x32_bf16(frag(vf[st][0]), frag(pb0), o[g][st], 0, 0, 0);
                o[g][st] = __builtin_amdgcn_mfma_f32_16x16x32_bf16(frag(vf[st][1]), frag(pb1), o[g][st], 0, 0, 0);
            }
        }

        asm volatile("s_barrier" ::: "memory");  // all reads of buf kt&1 done before overwrite
    }

    // epilogue: o[g] holds out^T (d=st*16+quad*4+r, q=l15). Normalize, transpose via LDS.
    unsigned short* Pw = Ps[wave];
    #pragma unroll
    for (int g = 0; g < 2; ++g) {
        float inv = 1.0f / l_s[g];
        #pragma unroll
        for (int st = 0; st < 4; ++st) {
            uint2 pk;
            pk.x = pack2bf(o[g][st][0]*inv, o[g][st][1]*inv);
            pk.y = pack2bf(o[g][st][2]*inv, o[g][st][3]*inv);
            *(uint2*)&Pw[g*1152 + l15*72 + st*16 + quad*4] = pk;
        }
    }
    asm volatile("s_waitcnt lgkmcnt(0)" ::: "memory");
    __syncthreads();

    const int qr = lane >> 2;          // 0..15
    const int dd = (lane & 3) * 16;    // 0,16,32,48
    #pragma unroll
    for (int g = 0; g < 2; ++g) {
        uint4 oa = *(const uint4*)&Pw[g*1152 + qr*72 + dd];
        uint4 ob = *(const uint4*)&Pw[g*1152 + qr*72 + dd + 8];
        const int mrow = b*SEQ + qt*128 + wave*32 + g*16 + qr;
        *(uint4*)&xb[(size_t)mrow*CDIM + h*HD + dd]     = oa;
        *(uint4*)&xb[(size_t)mrow*CDIM + h*HD + dd + 8] = ob;
    }
}

extern "C" void kernel_launch(void* const* d_in, const int* in_sizes, int n_in,
                              void* d_out, int out_size, void* d_ws, size_t ws_size,
                              hipStream_t stream)
{
    const float* q  = (const float*)d_in[0];
    const float* k  = (const float*)d_in[1];
    const float* v  = (const float*)d_in[2];
    const float* Wq = (const float*)d_in[3];
    const float* Wp = (const float*)d_in[4];
    const float* bp = (const float*)d_in[5];
    float* out = (float*)d_out;

    char* p = (char*)d_ws;
    auto carve = [&](size_t bytes) { char* r = p; p += (bytes + 255) & ~(size_t)255; return r; };
    unsigned short* Abuf   = (unsigned short*)carve((size_t)MROWS*K3C*2);
    unsigned short* Wqkvb  = (unsigned short*)carve((size_t)K3C*K3C*2);
    unsigned short* Wprojb = (unsigned short*)carve((size_t)CDIM*CDIM*2);
    unsigned short* qhb    = (unsigned short*)carve((size_t)BATCH*HEADS*SEQ*HD*2);
    unsigned short* khb    = (unsigned short*)carve((size_t)BATCH*HEADS*SEQ*HD*2);
    unsigned short* vtb    = (unsigned short*)carve((size_t)BATCH*HEADS*SEQ*HD*2);
    unsigned short* xbuf   = (unsigned short*)carve((size_t)MROWS*CDIM*2);

    cast_all<<<MROWS + 9216 + 1024, 256, 0, stream>>>(q, k, v, Wq, Wp, Abuf, Wqkvb, Wprojb);

    gemm256_qkv<<<dim3(256), 512, 0, stream>>>(Abuf, Wqkvb, qhb, khb, vtb);

    attention<<<dim3(SEQ/128, HEADS, BATCH), 256, 0, stream>>>(qhb, khb, vtb, xbuf);

    gemm_bt<1><<<dim3(MROWS/128, CDIM/128), 256, 0, stream>>>(
        xbuf, Wprojb, MROWS, CDIM, CDIM, nullptr, nullptr, nullptr, bp, out);
}

// Round 8
// 270.673 us; speedup vs baseline: 1.1274x; 1.0061x over previous
//
#include <hip/hip_runtime.h>
#include <hip/hip_bf16.h>
#include <stdint.h>

#define HEADS 16
#define HD 64
#define SEQ 2048
#define BATCH 2
#define CDIM 1024
#define MROWS (BATCH*SEQ)   // 4096
#define K3C (3*CDIM)        // 3072
// Q prescale: attn scale 1/8 times log2(e), so softmax uses exp2 directly
#define QSCALE 0.1803368801111244f

typedef __bf16 bf16x8 __attribute__((ext_vector_type(8)));
typedef float  f32x4  __attribute__((ext_vector_type(4)));

__device__ __forceinline__ unsigned short f2bf(float f) {
    __hip_bfloat16 h = __float2bfloat16(f);
    return __builtin_bit_cast(unsigned short, h);
}
__device__ __forceinline__ unsigned int pack2bf(float a, float b) {
    return (unsigned int)f2bf(a) | ((unsigned int)f2bf(b) << 16);
}
__device__ __forceinline__ bf16x8 frag(uint4 u) { return __builtin_bit_cast(bf16x8, u); }

// async global->LDS: per-lane global gather -> contiguous LDS (base + lane*16)
__device__ __forceinline__ void async16(const unsigned short* g, unsigned short* lds) {
    __builtin_amdgcn_global_load_lds(
        (const __attribute__((address_space(1))) unsigned int*)g,
        (__attribute__((address_space(3))) unsigned int*)lds, 16, 0, 0);
}

// inline-asm ds_read_b128 hidden from the LDS-DMA hazard pass (keeps the
// counted-vmcnt pipeline); must be followed by a counted lgkmcnt +
// sched_barrier(0) before consuming MFMAs (rule #18).
__device__ __forceinline__ void dsr(uint4& d, unsigned addr, unsigned imm) {
    asm volatile("ds_read_b128 %0, %1 offset:%c2" : "=v"(d) : "v"(addr), "i"(imm));
}

// ---------------- fused cast kernel ----------------
__global__ void cast_all(const float* __restrict__ q, const float* __restrict__ k,
                         const float* __restrict__ v, const float* __restrict__ Wq,
                         const float* __restrict__ Wp,
                         unsigned short* __restrict__ A, unsigned short* __restrict__ Wqb,
                         unsigned short* __restrict__ Wpb)
{
    const int bid = blockIdx.x;
    const int t = threadIdx.x;
    if (bid < MROWS) {
        const float* srcs[3] = {q, k, v};
        #pragma unroll
        for (int i = 0; i < 3; ++i) {
            float4 f = *(const float4*)(srcs[i] + (size_t)bid*CDIM + t*4);
            ushort4 s;
            s.x = f2bf(f.x); s.y = f2bf(f.y); s.z = f2bf(f.z); s.w = f2bf(f.w);
            *(ushort4*)(A + (size_t)bid*K3C + i*CDIM + t*4) = s;
        }
    } else if (bid < MROWS + 9216) {
        int idx = (bid - MROWS)*256 + t;
        float4 f = ((const float4*)Wq)[idx];
        ushort4 s;
        s.x = f2bf(f.x); s.y = f2bf(f.y); s.z = f2bf(f.z); s.w = f2bf(f.w);
        ((ushort4*)Wqb)[idx] = s;
    } else {
        int idx = (bid - MROWS - 9216)*256 + t;
        float4 f = ((const float4*)Wp)[idx];
        ushort4 s;
        s.x = f2bf(f.x); s.y = f2bf(f.y); s.z = f2bf(f.z); s.w = f2bf(f.w);
        ((ushort4*)Wpb)[idx] = s;
    }
}

// ---------------- m97-style bf16 GEMM (BK=32) — kept for the proj GEMM ----------------
template<int EPI>
__global__ __launch_bounds__(256, 2)
void gemm_bt(const unsigned short* __restrict__ A, const unsigned short* __restrict__ B,
             int M, int N, int K,
             unsigned short* __restrict__ qh, unsigned short* __restrict__ kh,
             unsigned short* __restrict__ vt,
             const float* __restrict__ bias, float* __restrict__ out)
{
    __shared__ __attribute__((aligned(16))) unsigned short As[128*32];
    __shared__ __attribute__((aligned(16))) unsigned short Bs[128*32];
    const int tid  = threadIdx.x;
    const int wave = tid >> 6;
    const int lane = tid & 63;
    const int l15  = lane & 15;
    const int quad = lane >> 4;
    const int wm = (wave >> 1) * 64;
    const int wn = (wave & 1) * 64;
    const int m0 = blockIdx.x * 128;
    const int n0 = blockIdx.y * 128;

    f32x4 acc[4][4] = {};

    const int srow = tid >> 2;
    const int sc8  = (tid & 3) * 8;

    for (int k0 = 0; k0 < K; k0 += 32) {
        #pragma unroll
        for (int t = 0; t < 2; ++t) {
            int row = t*64 + srow;
            const unsigned short* ga = A + (size_t)(m0 + row)*K + k0 + sc8;
            const unsigned short* gb = B + (size_t)(n0 + row)*K + k0 + sc8;
            async16(ga, &As[(t*256 + wave*64)*8]);
            async16(gb, &Bs[(t*256 + wave*64)*8]);
        }
        __syncthreads();
        uint4 af[4], bfv[4];
        #pragma unroll
        for (int i = 0; i < 4; ++i) {
            af[i]  = *(const uint4*)&As[(wm + i*16 + l15)*32 + quad*8];
            bfv[i] = *(const uint4*)&Bs[(wn + i*16 + l15)*32 + quad*8];
        }
        #pragma unroll
        for (int mi = 0; mi < 4; ++mi)
            #pragma unroll
            for (int ni = 0; ni < 4; ++ni)
                acc[mi][ni] = __builtin_amdgcn_mfma_f32_16x16x32_bf16(
                    frag(af[mi]), frag(bfv[ni]), acc[mi][ni], 0, 0, 0);
        __syncthreads();
    }

    if constexpr (EPI == 0) {
        #pragma unroll
        for (int mi = 0; mi < 4; ++mi) {
            int row0 = m0 + wm + mi*16 + quad*4;
            int b  = row0 >> 11;
            int nq = row0 & 2047;
            #pragma unroll
            for (int ni = 0; ni < 4; ++ni) {
                int col   = n0 + wn + ni*16 + l15;
                int which = col >> 10;
                int h     = (col >> 6) & 15;
                int d     = col & 63;
                int bh    = b*HEADS + h;
                if (which == 2) {
                    ushort4 pv;
                    pv.x = f2bf(acc[mi][ni][0]);
                    pv.y = f2bf(acc[mi][ni][1]);
                    pv.z = f2bf(acc[mi][ni][2]);
                    pv.w = f2bf(acc[mi][ni][3]);
                    *(ushort4*)&vt[((size_t)bh*HD + d)*SEQ + nq] = pv;
                } else {
                    unsigned short* dst = (which == 0) ? qh : kh;
                    float sc = (which == 0) ? QSCALE : 1.0f;
                    #pragma unroll
                    for (int r = 0; r < 4; ++r)
                        dst[((size_t)bh*SEQ + nq + r)*HD + d] = f2bf(acc[mi][ni][r] * sc);
                }
            }
        }
    } else {
        #pragma unroll
        for (int mi = 0; mi < 4; ++mi) {
            int row0 = m0 + wm + mi*16 + quad*4;
            #pragma unroll
            for (int ni = 0; ni < 4; ++ni) {
                int col  = n0 + wn + ni*16 + l15;
                float bv = bias[col];
                #pragma unroll
                for (int r = 0; r < 4; ++r)
                    out[(size_t)(row0 + r)*N + col] = acc[mi][ni][r] + bv;
            }
        }
    }
}

// ---------------- 256x192 1-phase split-wait bf16 GEMM for the QKV projection ----------
// Round-8 delta (schedule-preserving): wave decomposition 2Mx4N -> 4Mx2N.
// LDS-read amplification per K-tile drops 176KB -> 160KB (A read by 2 N-waves
// instead of 4 was wrong way; A amp = nN = 2, B amp = nM = 4: 2*32 + 4*24 = 160)
// with identical MFMA count, LDS layout, staging, swizzles, vt permutation.
// Wave tile 64x96, acc[4][6]; reads/wave: A 4mi x 2kc = 8, B 6ni x 2kc = 12.
// Also: stage(t+2) moved to right after the mid-barrier (reads of that buffer
// provably retired: lgkmcnt(0)+barrier) -> DMA gets the kc1-MFMA window of
// head start before the end-of-tile counted vmcnt(7).
#define NT48 48

__global__ __launch_bounds__(512, 2)
void gemm256_qkv(const unsigned short* __restrict__ A, const unsigned short* __restrict__ B,
                 unsigned short* __restrict__ qh, unsigned short* __restrict__ kh,
                 unsigned short* __restrict__ vt)
{
    __shared__ __attribute__((aligned(16))) unsigned short As[2*16384]; // 2 x 32KB
    __shared__ __attribute__((aligned(16))) unsigned short Bs[2*12288]; // 2 x 24KB

    const int tid  = threadIdx.x;
    const int wave = tid >> 6;
    const int lane = tid & 63;
    const int l15  = lane & 15;
    const int quad = lane >> 4;
    const int wr   = wave >> 1;   // 0..3  (M: 64 rows each)
    const int wc   = wave & 1;    // 0..1  (N: 96 cols each)

    // XCD-aware bijective swizzle: 256 blocks, 256 % 8 == 0, 32 per XCD
    const int id  = blockIdx.x;
    const int swz = (id & 7)*32 + (id >> 3);
    const int m0  = (swz & 15) * 256;   // 16 M-tiles
    const int n0  = (swz >> 4) * 192;   // 16 N-tiles

    size_t aSrc[4]; size_t bSrc[3];
    #pragma unroll
    for (int u = 0; u < 4; ++u) {
        int P  = u*8192 + tid*16;
        int st = P >> 10, q = P & 1023;
        int ql = q ^ (((q >> 9) & 1) << 5);
        int row = m0 + (st >> 1)*16 + (ql >> 6);
        int kel = (st & 1)*32 + ((ql & 63) >> 1);
        aSrc[u] = (size_t)row*K3C + kel;
    }
    #pragma unroll
    for (int u = 0; u < 3; ++u) {
        int P  = u*8192 + tid*16;
        int st = P >> 10, q = P & 1023;
        int ql = q ^ (((q >> 9) & 1) << 5);
        int row = n0 + (st >> 1)*16 + (ql >> 6);
        int kel = (st & 1)*32 + ((ql & 63) >> 1);
        bSrc[u] = (size_t)row*K3C + kel;
    }
    const int wdst = wave*512;

    auto stage = [&](int t) {
        const int hb = t & 1;
        #pragma unroll
        for (int u = 0; u < 4; ++u)
            async16(A + aSrc[u] + t*64, As + hb*16384 + u*4096 + wdst);
        #pragma unroll
        for (int u = 0; u < 3; ++u)
            async16(B + bSrc[u] + t*64, Bs + hb*12288 + u*4096 + wdst);
    };

    const unsigned lanebyte = (unsigned)((l15*64 + quad*16) ^ ((l15 & 8) << 2));
    const unsigned aAddr = (unsigned)(uintptr_t)&As[0] + lanebyte + (unsigned)(wr*8192);
    const unsigned bAddr = (unsigned)(uintptr_t)&Bs[0] + lanebyte + (unsigned)(wc*12288);

    f32x4 acc[4][6] = {};

    stage(0); stage(1);
    asm volatile("s_waitcnt vmcnt(7)" ::: "memory");
    __builtin_amdgcn_s_barrier();

    for (int tt = 0; tt < NT48; tt += 2) {
        #pragma unroll
        for (int hb = 0; hb < 2; ++hb) {
            const int t = tt + hb;                       // t&1 == hb
            uint4 a0[4], b0[6], a1[4], b1[6];

            // issue all reads, kc0 cluster first (10), then kc1 cluster (10)
            #pragma unroll
            for (int mi = 0; mi < 4; ++mi)
                dsr(a0[mi], aAddr, hb*32768 + mi*2048);
            #pragma unroll
            for (int ni = 0; ni < 6; ++ni)
                dsr(b0[ni], bAddr, hb*24576 + ni*2048);
            #pragma unroll
            for (int mi = 0; mi < 4; ++mi)
                dsr(a1[mi], aAddr, hb*32768 + mi*2048 + 1024);
            #pragma unroll
            for (int ni = 0; ni < 6; ++ni)
                dsr(b1[ni], bAddr, hb*24576 + ni*2048 + 1024);

            // kc0 operands ready; kc1 reads still in flight behind the MFMAs
            asm volatile("s_waitcnt lgkmcnt(10)" ::: "memory");
            __builtin_amdgcn_sched_barrier(0);
            __builtin_amdgcn_s_setprio(1);
            #pragma unroll
            for (int mi = 0; mi < 4; ++mi)
                #pragma unroll
                for (int ni = 0; ni < 6; ++ni)
                    acc[mi][ni] = __builtin_amdgcn_mfma_f32_16x16x32_bf16(
                        frag(a0[mi]), frag(b0[ni]), acc[mi][ni], 0, 0, 0);
            __builtin_amdgcn_s_setprio(0);

            // all of this wave's reads done; barrier => ALL waves' reads done
            asm volatile("s_waitcnt lgkmcnt(0)" ::: "memory");
            __builtin_amdgcn_sched_barrier(0);
            __builtin_amdgcn_s_barrier();

            // counted prefetch issued EARLY: buf hb is safe to overwrite here,
            // and the DMA flies under the kc1 MFMA cluster before vmcnt(7)
            if (t + 2 < NT48) stage(t + 2);

            __builtin_amdgcn_s_setprio(1);
            #pragma unroll
            for (int mi = 0; mi < 4; ++mi)
                #pragma unroll
                for (int ni = 0; ni < 6; ++ni)
                    acc[mi][ni] = __builtin_amdgcn_mfma_f32_16x16x32_bf16(
                        frag(a1[mi]), frag(b1[ni]), acc[mi][ni], 0, 0, 0);
            __builtin_amdgcn_s_setprio(0);

            if (t + 2 < NT48)      { asm volatile("s_waitcnt vmcnt(7)" ::: "memory"); }
            else if (t + 1 < NT48) { asm volatile("s_waitcnt vmcnt(0)" ::: "memory"); }
            __builtin_amdgcn_s_barrier();
        }
    }

    // epilogue: qh (scaled), kh, vt (transposed + PV-slot permuted keys)
    #pragma unroll
    for (int mi = 0; mi < 4; ++mi) {
        const int row0 = m0 + wr*64 + mi*16 + quad*4;
        const int b  = row0 >> 11;
        const int nq = row0 & 2047;
        #pragma unroll
        for (int ni = 0; ni < 6; ++ni) {
            const int col   = n0 + wc*96 + ni*16 + l15;
            const int which = col >> 10;
            const int h     = (col >> 6) & 15;
            const int d     = col & 63;
            const int bh_   = b*HEADS + h;
            if (which == 2) {
                ushort4 pv;
                pv.x = f2bf(acc[mi][ni][0]);
                pv.y = f2bf(acc[mi][ni][1]);
                pv.z = f2bf(acc[mi][ni][2]);
                pv.w = f2bf(acc[mi][ni][3]);
                // pi^-1: key L = mi*16 + quad*4 + r -> (quad + 4*(mi>>1))*8 + (mi&1)*4 + r
                const int nq2 = (nq & ~63) | ((quad + ((mi >> 1) << 2)) << 3) | ((mi & 1) << 2);
                *(ushort4*)&vt[((size_t)bh_*HD + d)*SEQ + nq2] = pv;
            } else {
                unsigned short* dst = (which == 0) ? qh : kh;
                float sc = (which == 0) ? QSCALE : 1.0f;
                #pragma unroll
                for (int r = 0; r < 4; ++r)
                    dst[((size_t)bh_*SEQ + nq + r)*HD + d] = f2bf(acc[mi][ni][r] * sc);
            }
        }
    }
}

// ---------------- flash attention: in-register P (zero-shuffle PV) ----------------
// Unchanged from round 7 (harness-verified): vt keys pre-permuted so the PV
// B-fragment is the lane's own packed P registers; inline-asm K/V reads with
// counted lgkmcnt(8); defer-max THR=8.
__global__ __launch_bounds__(256, 2)
void attention(const unsigned short* __restrict__ qh, const unsigned short* __restrict__ kh,
               const unsigned short* __restrict__ vt, unsigned short* __restrict__ xb)
{
    const int qt = blockIdx.x;          // 0..15 (tiles of 128 q)
    const int h  = blockIdx.y;
    const int b  = blockIdx.z;
    const int bh = b*HEADS + h;
    const int tid  = threadIdx.x;
    const int wave = tid >> 6;
    const int lane = tid & 63;
    const int l15  = lane & 15;
    const int quad = lane >> 4;

    __shared__ __attribute__((aligned(16))) unsigned short Ks[2][64*64];
    __shared__ __attribute__((aligned(16))) unsigned short Vs[2][64*64];
    __shared__ __attribute__((aligned(16))) unsigned short Ps[4][2*16*72];

    const unsigned short* Qp = qh + ((size_t)bh*SEQ + qt*128 + wave*32)*HD;
    const unsigned short* Kp = kh + (size_t)bh*SEQ*HD;
    const unsigned short* Vp = vt + (size_t)bh*HD*SEQ;

    auto stage = [&](int kt, int bufI) {
        #pragma unroll
        for (int t = 0; t < 2; ++t) {
            int c  = t*256 + wave*64 + lane;   // chunk index 0..511
            int r  = c >> 3;
            int cc = (c & 7) ^ (r & 7);
            async16(Kp + (size_t)(kt*64 + r)*HD + cc*8,
                    &Ks[bufI][(t*256 + wave*64)*8]);
            async16(Vp + (size_t)r*SEQ + kt*64 + cc*8,
                    &Vs[bufI][(t*256 + wave*64)*8]);
        }
    };

    stage(0, 0);

    uint4 qf[2][2];
    #pragma unroll
    for (int g = 0; g < 2; ++g) {
        qf[g][0] = *(const uint4*)(Qp + (size_t)(g*16 + l15)*HD + quad*8);
        qf[g][1] = *(const uint4*)(Qp + (size_t)(g*16 + l15)*HD + 32 + quad*8);
    }

    f32x4 o[2][4] = {};
    float m_s[2] = {-INFINITY, -INFINITY};
    float l_s[2] = {0.f, 0.f};

    const int x7 = l15 & 7;
    const unsigned ksBase = (unsigned)(uintptr_t)&Ks[0][0];
    const unsigned vsBase = (unsigned)(uintptr_t)&Vs[0][0];
    const unsigned laneA  = (unsigned)(l15*128 + (quad ^ x7)*16);        // chunk quad
    const unsigned laneB  = (unsigned)(l15*128 + ((quad ^ x7) ^ 4)*16);  // chunk 4+quad

    for (int kt = 0; kt < SEQ/64; ++kt) {
        stage((kt + 1) & 31, (kt + 1) & 1);
        asm volatile("s_waitcnt vmcnt(4)" ::: "memory");  // tile kt (and Q) landed
        asm volatile("s_barrier" ::: "memory");

        const unsigned bufo = (unsigned)((kt & 1) * 8192);
        const unsigned ka = ksBase + bufo + laneA, kb = ksBase + bufo + laneB;
        const unsigned va = vsBase + bufo + laneA, vb = vsBase + bufo + laneB;

        uint4 kf[4][2], vf[4][2];
        #pragma unroll
        for (int st = 0; st < 4; ++st) { dsr(kf[st][0], ka, st*2048); dsr(kf[st][1], kb, st*2048); }
        #pragma unroll
        for (int st = 0; st < 4; ++st) { dsr(vf[st][0], va, st*2048); dsr(vf[st][1], vb, st*2048); }

        asm volatile("s_waitcnt lgkmcnt(8)" ::: "memory");   // K ready; V drains behind QK^T
        __builtin_amdgcn_sched_barrier(0);

        f32x4 s[2][4];
        #pragma unroll
        for (int st = 0; st < 4; ++st)
            #pragma unroll
            for (int g = 0; g < 2; ++g) {
                f32x4 z = {};
                z = __builtin_amdgcn_mfma_f32_16x16x32_bf16(frag(kf[st][0]), frag(qf[g][0]), z, 0, 0, 0);
                z = __builtin_amdgcn_mfma_f32_16x16x32_bf16(frag(kf[st][1]), frag(qf[g][1]), z, 0, 0, 0);
                s[g][st] = z;
            }

        unsigned W[2][8];
        #pragma unroll
        for (int g = 0; g < 2; ++g) {
            float mloc = s[g][0][0];
            #pragma unroll
            for (int st = 0; st < 4; ++st)
                #pragma unroll
                for (int r = 0; r < 4; ++r)
                    mloc = fmaxf(mloc, s[g][st][r]);
            mloc = fmaxf(mloc, __shfl_xor(mloc, 16));
            mloc = fmaxf(mloc, __shfl_xor(mloc, 32));

            // defer-max: keep stale m while growth <= 8 (P bounded by 2^8)
            if (!__all(mloc - m_s[g] <= 8.0f)) {
                float mn = fmaxf(m_s[g], mloc);
                float al = __builtin_amdgcn_exp2f(m_s[g] - mn);
                m_s[g] = mn;
                l_s[g] *= al;
                #pragma unroll
                for (int st = 0; st < 4; ++st)
                    #pragma unroll
                    for (int r = 0; r < 4; ++r)
                        o[g][st][r] *= al;
            }
            const float mn = m_s[g];

            float rs = 0.f;
            float p[4][4];
            #pragma unroll
            for (int st = 0; st < 4; ++st)
                #pragma unroll
                for (int r = 0; r < 4; ++r) {
                    p[st][r] = __builtin_amdgcn_exp2f(s[g][st][r] - mn);
                    rs += p[st][r];
                }
            rs += __shfl_xor(rs, 16);
            rs += __shfl_xor(rs, 32);
            l_s[g] += rs;

            #pragma unroll
            for (int st = 0; st < 4; ++st) {
                W[g][st*2 + 0] = pack2bf(p[st][0], p[st][1]);
                W[g][st*2 + 1] = pack2bf(p[st][2], p[st][3]);
            }
        }

        asm volatile("s_waitcnt lgkmcnt(0)" ::: "memory");   // V frags ready
        __builtin_amdgcn_sched_barrier(0);

        #pragma unroll
        for (int g = 0; g < 2; ++g) {
            uint4 pb0, pb1;
            pb0.x = W[g][0]; pb0.y = W[g][1]; pb0.z = W[g][2]; pb0.w = W[g][3];
            pb1.x = W[g][4]; pb1.y = W[g][5]; pb1.z = W[g][6]; pb1.w = W[g][7];
            #pragma unroll
            for (int st = 0; st < 4; ++st) {
                o[g][st] = __builtin_amdgcn_mfma_f32_16x16x32_bf16(frag(vf[st][0]), frag(pb0), o[g][st], 0, 0, 0);
                o[g][st] = __builtin_amdgcn_mfma_f32_16x16x32_bf16(frag(vf[st][1]), frag(pb1), o[g][st], 0, 0, 0);
            }
        }

        asm volatile("s_barrier" ::: "memory");  // all reads of buf kt&1 done before overwrite
    }

    // epilogue: o[g] holds out^T (d=st*16+quad*4+r, q=l15). Normalize, transpose via LDS.
    unsigned short* Pw = Ps[wave];
    #pragma unroll
    for (int g = 0; g < 2; ++g) {
        float inv = 1.0f / l_s[g];
        #pragma unroll
        for (int st = 0; st < 4; ++st) {
            uint2 pk;
            pk.x = pack2bf(o[g][st][0]*inv, o[g][st][1]*inv);
            pk.y = pack2bf(o[g][st][2]*inv, o[g][st][3]*inv);
            *(uint2*)&Pw[g*1152 + l15*72 + st*16 + quad*4] = pk;
        }
    }
    asm volatile("s_waitcnt lgkmcnt(0)" ::: "memory");
    __syncthreads();

    const int qr = lane >> 2;          // 0..15
    const int dd = (lane & 3) * 16;    // 0,16,32,48
    #pragma unroll
    for (int g = 0; g < 2; ++g) {
        uint4 oa = *(const uint4*)&Pw[g*1152 + qr*72 + dd];
        uint4 ob = *(const uint4*)&Pw[g*1152 + qr*72 + dd + 8];
        const int mrow = b*SEQ + qt*128 + wave*32 + g*16 + qr;
        *(uint4*)&xb[(size_t)mrow*CDIM + h*HD + dd]     = oa;
        *(uint4*)&xb[(size_t)mrow*CDIM + h*HD + dd + 8] = ob;
    }
}

extern "C" void kernel_launch(void* const* d_in, const int* in_sizes, int n_in,
                              void* d_out, int out_size, void* d_ws, size_t ws_size,
                              hipStream_t stream)
{
    const float* q  = (const float*)d_in[0];
    const float* k  = (const float*)d_in[1];
    const float* v  = (const float*)d_in[2];
    const float* Wq = (const float*)d_in[3];
    const float* Wp = (const float*)d_in[4];
    const float* bp = (const float*)d_in[5];
    float* out = (float*)d_out;

    char* p = (char*)d_ws;
    auto carve = [&](size_t bytes) { char* r = p; p += (bytes + 255) & ~(size_t)255; return r; };
    unsigned short* Abuf   = (unsigned short*)carve((size_t)MROWS*K3C*2);
    unsigned short* Wqkvb  = (unsigned short*)carve((size_t)K3C*K3C*2);
    unsigned short* Wprojb = (unsigned short*)carve((size_t)CDIM*CDIM*2);
    unsigned short* qhb    = (unsigned short*)carve((size_t)BATCH*HEADS*SEQ*HD*2);
    unsigned short* khb    = (unsigned short*)carve((size_t)BATCH*HEADS*SEQ*HD*2);
    unsigned short* vtb    = (unsigned short*)carve((size_t)BATCH*HEADS*SEQ*HD*2);
    unsigned short* xbuf   = (unsigned short*)carve((size_t)MROWS*CDIM*2);

    cast_all<<<MROWS + 9216 + 1024, 256, 0, stream>>>(q, k, v, Wq, Wp, Abuf, Wqkvb, Wprojb);

    gemm256_qkv<<<dim3(256), 512, 0, stream>>>(Abuf, Wqkvb, qhb, khb, vtb);

    attention<<<dim3(SEQ/128, HEADS, BATCH), 256, 0, stream>>>(qhb, khb, vtb, xbuf);

    gemm_bt<1><<<dim3(MROWS/128, CDIM/128), 256, 0, stream>>>(
        xbuf, Wprojb, MROWS, CDIM, CDIM, nullptr, nullptr, nullptr, bp, out);
}